// Round 1
// baseline (6890.830 us; speedup 1.0000x reference)
//
#include <hip/hip_runtime.h>
#include <stdint.h>

typedef unsigned int u32;
typedef __attribute__((ext_vector_type(8))) short bf16x8;
typedef __attribute__((ext_vector_type(4))) float f32x4;
typedef __attribute__((ext_vector_type(4))) int i32x4;
typedef __attribute__((ext_vector_type(2))) int i32x2;

#define DEV static __device__ __forceinline__

DEV short f2bf(float f){ u32 u=__float_as_uint(f); return (short)((u + 0x7fffu + ((u>>16)&1u))>>16); }
DEV float bf2f(short s){ return __uint_as_float(((u32)(unsigned short)s)<<16); }
DEV float sig_p(float x){ return 1.f/(1.f+expf(-x)); }
DEV float tanh_fast(float x){ float e=__expf(2.f*x); return 1.f-2.f/(e+1.f); }
DEV void spin_ge(u32* c, u32 tgt){
  while(__hip_atomic_load(c,__ATOMIC_RELAXED,__HIP_MEMORY_SCOPE_AGENT)<tgt) __builtin_amdgcn_s_sleep(2);
  __threadfence();
}

// ---------------- convert / transpose kernels ----------------

__global__ void cvt1d(const float* __restrict__ in, short* __restrict__ out, int n){
  int i = blockIdx.x*256 + threadIdx.x;
  if (i < n) out[i] = f2bf(in[i]);
}

// in f32 [R][C] (row stride C) -> out bf16 [Cpad][R], rows >= C zero-filled
__global__ void tconv(const float* __restrict__ in, short* __restrict__ out, int R, int C, int Cpad){
  __shared__ float t[32][33];
  int tx = threadIdx.x, ty = threadIdx.y;
  int c0 = blockIdx.x*32, r0 = blockIdx.y*32;
#pragma unroll
  for (int j=0;j<4;++j){
    int r = r0 + ty + 8*j, c = c0 + tx;
    t[ty+8*j][tx] = (c < C) ? in[(size_t)r*C + c] : 0.f;
  }
  __syncthreads();
#pragma unroll
  for (int j=0;j<4;++j){
    int oc = c0 + ty + 8*j;          // out row (= original col)
    out[(size_t)oc*R + r0 + tx] = f2bf(t[tx][ty+8*j]);
  }
}

// batched transpose: in bf16 [NB][Dd][32] -> out bf16 [NB*32][Dd]
__global__ void btrans(const short* __restrict__ in, short* __restrict__ out, int Dd){
  __shared__ short t[32][33];
  int tx = threadIdx.x, ty = threadIdx.y;
  int d0 = blockIdx.x*32, s = blockIdx.y;
#pragma unroll
  for (int j=0;j<4;++j)
    t[ty+8*j][tx] = in[((size_t)s*Dd + d0 + ty + 8*j)*32 + tx];
  __syncthreads();
#pragma unroll
  for (int j=0;j<4;++j)
    out[((size_t)(s*32 + ty + 8*j))*Dd + d0 + tx] = t[tx][ty+8*j];
}

// embedding gather: X[(s*32+b)][d] = bf16(emb[tok[b][s]][d])
__global__ void embed_k(const int* __restrict__ tok, const float* __restrict__ emb, short* __restrict__ X){
  int row = blockIdx.x;               // (s,b)
  int s = row >> 5, b = row & 31;
  int tv = tok[b*128 + s];
  X[(size_t)row*256 + threadIdx.x] = f2bf(emb[(size_t)tv*256 + threadIdx.x]);
}

// ---------------- MFMA GEMM  C = A[M,K] * B (B given as BT[Npad][K]) ----------------
// MODE 1: out bf16 T-layout [s][Ntot][32], + bias
// MODE 2: out f32 d_out exp(logit+bias) with (s,b)->(b,s) row remap + psum partials
// MODE 3: out bf16 row-major [M][Nreal], (+bias if non-null)
template<int MODE>
__global__ __launch_bounds__(256) void gemm_k(
  const short* __restrict__ A, const short* __restrict__ BT,
  const float* __restrict__ bias, void* __restrict__ outp,
  float* __restrict__ psum, int Nreal, int K, int Ntot)
{
  const int m0 = blockIdx.y * 128, n0 = blockIdx.x * 128;
  const int tid = threadIdx.x, l = tid & 63, wv = tid >> 6;
  const int wm = wv >> 1, wn = wv & 1;
  __shared__ __align__(16) short As[128*64];
  __shared__ __align__(16) short Bs[128*64];
  f32x4 acc[4][4];
#pragma unroll
  for (int i=0;i<4;++i)
#pragma unroll
    for (int j=0;j<4;++j) acc[i][j] = (f32x4){0.f,0.f,0.f,0.f};

  const int nkb = K >> 6;
  for (int kb=0; kb<nkb; ++kb){
#pragma unroll
    for (int i=0;i<4;++i){
      int si = tid + i*256;
      int row = si >> 3, seg = si & 7;
      u32 off = (u32)(row*128 + seg*16) ^ (u32)((row&7)<<4);
      *(i32x4*)((char*)As + off) = *(const i32x4*)(A + (size_t)(m0+row)*K + kb*64 + seg*8);
      *(i32x4*)((char*)Bs + off) = *(const i32x4*)(BT + (size_t)(n0+row)*K + kb*64 + seg*8);
    }
    __syncthreads();
#pragma unroll
    for (int kt=0; kt<2; ++kt){
      bf16x8 af[4], bfv[4];
      int seg = kt*4 + (l>>4);
#pragma unroll
      for (int f=0; f<4; ++f){
        int ra = wm*64 + f*16 + (l&15);
        af[f]  = *(const bf16x8*)((char*)As + (((u32)(ra*128 + seg*16)) ^ ((u32)(ra&7)<<4)));
        int rb = wn*64 + f*16 + (l&15);
        bfv[f] = *(const bf16x8*)((char*)Bs + (((u32)(rb*128 + seg*16)) ^ ((u32)(rb&7)<<4)));
      }
#pragma unroll
      for (int mf=0; mf<4; ++mf)
#pragma unroll
        for (int nf=0; nf<4; ++nf)
          acc[mf][nf] = __builtin_amdgcn_mfma_f32_16x16x32_bf16(af[mf], bfv[nf], acc[mf][nf], 0,0,0);
    }
    __syncthreads();
  }

  if (MODE == 1){
    short* oT = (short*)outp;
#pragma unroll
    for (int mf=0; mf<4; ++mf){
      int r0 = m0 + wm*64 + mf*16 + ((l>>4)<<2);
      int s = r0 >> 5, b0 = r0 & 31;
#pragma unroll
      for (int nf=0; nf<4; ++nf){
        int col = n0 + wn*64 + nf*16 + (l&15);
        float bv = bias ? bias[col] : 0.f;
        short tmp[4];
#pragma unroll
        for (int j=0;j<4;++j) tmp[j] = f2bf(acc[mf][nf][j] + bv);
        *(i32x2*)(oT + ((size_t)s*Ntot + col)*32 + b0) = *(i32x2*)tmp;
      }
    }
  } else if (MODE == 3){
    short* o = (short*)outp;
#pragma unroll
    for (int mf=0; mf<4; ++mf){
      int r0 = m0 + wm*64 + mf*16 + ((l>>4)<<2);
#pragma unroll
      for (int nf=0; nf<4; ++nf){
        int col = n0 + wn*64 + nf*16 + (l&15);
        if (col < Nreal){
          float bv = bias ? bias[col] : 0.f;
#pragma unroll
          for (int j=0;j<4;++j) o[(size_t)(r0+j)*Nreal + col] = f2bf(acc[mf][nf][j] + bv);
        }
      }
    }
  } else { // MODE 2
    float* o = (float*)outp;
    int ncb = gridDim.x;
    float rs[4][4];
#pragma unroll
    for (int i=0;i<4;++i)
#pragma unroll
      for (int j=0;j<4;++j) rs[i][j]=0.f;
#pragma unroll
    for (int mf=0; mf<4; ++mf){
      int r0 = m0 + wm*64 + mf*16 + ((l>>4)<<2);
      int s = r0 >> 5, b0 = r0 & 31;
#pragma unroll
      for (int nf=0; nf<4; ++nf){
        int col = n0 + wn*64 + nf*16 + (l&15);
        if (col < Nreal){
          float bv = bias[col];
#pragma unroll
          for (int j=0;j<4;++j){
            float e = __expf(acc[mf][nf][j] + bv);
            o[(size_t)((b0+j)*128 + s)*Nreal + col] = e;
            rs[mf][j] += e;
          }
        }
      }
    }
#pragma unroll
    for (int mf=0; mf<4; ++mf)
#pragma unroll
      for (int j=0;j<4;++j){
        float v = rs[mf][j];
        v += __shfl_xor(v,1); v += __shfl_xor(v,2); v += __shfl_xor(v,4); v += __shfl_xor(v,8);
        if ((l&15)==0){
          int r = m0 + wm*64 + mf*16 + ((l>>4)<<2) + j;
          int orow = (r&31)*128 + (r>>5);
          psum[(size_t)orow*(2*ncb) + blockIdx.x*2 + wn] = v;
        }
      }
  }
}

// ---------------- encoder scan (64 WGs x 384 thr, grid barrier) ----------------
__global__ __launch_bounds__(384) void enc_scan(
  const short* __restrict__ gxfT, const short* __restrict__ gxbT,
  const short* __restrict__ WhfT, const short* __restrict__ WhbT,
  const float* __restrict__ brf, const float* __restrict__ brb,
  float* __restrict__ hT, float* __restrict__ hrow,
  short* __restrict__ encT, u32* __restrict__ cnt)
{
  const int tid = threadIdx.x, wg = blockIdx.x;
  const int dir = wg >> 5, ws = wg & 31, c0 = ws*16;
  const short* gxT = dir ? gxbT : gxfT;
  const short* WT  = dir ? WhbT : WhfT;
  const float* br  = dir ? brb  : brf;
  float* hTd   = hT   + dir*32768;   // [2][512][32]
  float* hrowd = hrow + dir*32768;   // [2][32][512]
  const int l = tid & 63, wv = tid >> 6;
  const int m = wv & 1, g = wv >> 1;          // 6 waves: 2m x 3g

  bf16x8 bfrag[16];
  {
    int col = g*512 + c0 + (l&15);
    const short* bp = WT + (size_t)col*512 + ((l>>4)<<3);
#pragma unroll
    for (int kt=0; kt<16; ++kt) bfrag[kt] = *(const bf16x8*)(bp + kt*32);
  }
  __shared__ __align__(16) float accL[48][36];

  for (int t=0; t<128; ++t){
    const int s = dir ? (127-t) : t;
    const int cur = t & 1, nxt = cur ^ 1;
    // gh = h @ Wh (A from global h_row, B persistent)
    {
      int brow2 = m*16 + (l&15);
      const float* ap = hrowd + cur*16384 + brow2*512 + ((l>>4)<<3);
      f32x4 acc = (f32x4){0.f,0.f,0.f,0.f};
#pragma unroll
      for (int kt=0; kt<16; ++kt){
        f32x4 u = *(const f32x4*)(ap + kt*32);
        f32x4 w = *(const f32x4*)(ap + kt*32 + 4);
        bf16x8 a8;
#pragma unroll
        for (int i=0;i<4;++i){ a8[i]=f2bf(u[i]); a8[4+i]=f2bf(w[i]); }
        acc = __builtin_amdgcn_mfma_f32_16x16x32_bf16(a8, bfrag[kt], acc, 0,0,0);
      }
      *(f32x4*)&accL[g*16 + (l&15)][m*16 + ((l>>4)<<2)] = acc;
    }
    __syncthreads();
    // gates
    for (int o = tid; o < 512; o += 384){
      int hc = o >> 5, b = o & 31;
      int hcol = c0 + hc;
      size_t gb = ((size_t)s*1536 + hcol)*32 + b;
      float xz = bf2f(gxT[gb]);
      float xr = bf2f(gxT[gb + 512*32]);
      float xh = bf2f(gxT[gb + 1024*32]);
      float gz = accL[hc][b]      + br[hcol];
      float gr = accL[16+hc][b]   + br[512+hcol];
      float gh = accL[32+hc][b]   + br[1024+hcol];
      float z = sig_p(xz + gz);
      float r = sig_p(xr + gr);
      float hcand = tanhf(xh + r*gh);
      float hp = hTd[cur*16384 + hcol*32 + b];
      float hn = z*hp + (1.f-z)*hcand;
      hTd[nxt*16384 + hcol*32 + b] = hn;
      hrowd[nxt*16384 + b*512 + hcol] = hn;
      encT[((size_t)s*1024 + dir*512 + hcol)*32 + b] = f2bf(hn);
    }
    __syncthreads();
    if (tid == 0){ __threadfence(); atomicAdd(cnt,1u); spin_ge(cnt, 64u*(t+1)); }
    __syncthreads();
  }
}

// ---------------- decoder scan (160 WGs x 512 thr) ----------------
__global__ __launch_bounds__(512) void dec_scan(
  const short* __restrict__ gxeT, const short* __restrict__ encxT,
  const short* __restrict__ WhdT, const float* __restrict__ brd,
  const short* __restrict__ Wa, const short* __restrict__ Uenc, const float* __restrict__ Va,
  float* __restrict__ hTd, float* __restrict__ hrowd,
  float* __restrict__ alphaT, short* __restrict__ decT,
  u32* __restrict__ hcnt, u32* __restrict__ acnt)
{
  const int tid = threadIdx.x, wg = blockIdx.x;
  const int l = tid & 63, wv = tid >> 6;

  // gates-WG shared
  __shared__ __align__(16) float accL[4][16][36];
  __shared__ float gxL[12][32];
  __shared__ float alphaL[4096];
  // att-WG shared
  __shared__ float hs[512];
  __shared__ float whp[128*5];
  __shared__ float whv[128];
  __shared__ float scp[128*5];
  __shared__ float sc[128];
  __shared__ float red[4];
  __shared__ float vL[128];

  if (wg < 128){
    // ---- GRU gates workgroup: h-cols j*4..j*4+3 ----
    const int j = wg;
    const int m = wv & 1, kq = wv >> 1;   // 8 waves
    bf16x8 bfr[4];
    {
      int nc = l & 15;
      int col = (nc < 12) ? ((nc>>2)*512 + j*4 + (nc&3)) : 0;
      const short* bp = WhdT + (size_t)col*512 + ((l>>4)<<3);
#pragma unroll
      for (int i=0;i<4;++i) bfr[i] = *(const bf16x8*)(bp + (kq*4+i)*32);
    }
    for (int t=0; t<128; ++t){
      if (tid == 0) spin_ge(hcnt, 128u*(u32)t);
      __syncthreads();
      const int cur = t & 1, nxt = cur ^ 1;
      // gh partial MFMA
      {
        int brow2 = m*16 + (l&15);
        const float* ap = hrowd + cur*16384 + brow2*512 + ((l>>4)<<3);
        f32x4 acc = (f32x4){0.f,0.f,0.f,0.f};
#pragma unroll
        for (int i=0;i<4;++i){
          int kt = kq*4 + i;
          f32x4 u = *(const f32x4*)(ap + kt*32);
          f32x4 w = *(const f32x4*)(ap + kt*32 + 4);
          bf16x8 a8;
#pragma unroll
          for (int q=0;q<4;++q){ a8[q]=f2bf(u[q]); a8[4+q]=f2bf(w[q]); }
          acc = __builtin_amdgcn_mfma_f32_16x16x32_bf16(a8, bfr[i], acc, 0,0,0);
        }
        *(f32x4*)&accL[kq][l&15][m*16 + ((l>>4)<<2)] = acc;
      }
      __syncthreads();
      if (tid == 0) spin_ge(acnt, 32u*(u32)(t+1));
      __syncthreads();
#pragma unroll
      for (int i=0;i<8;++i){ int idx = tid + i*512; alphaL[idx] = alphaT[idx]; }
      __syncthreads();
      // gx = gx_enc (incl bi_d) + sum_s alpha * ENCX
      if (tid < 384){
        int gcI = tid >> 5, b = tid & 31;
        int gcol = (gcI>>2)*512 + j*4 + (gcI&3);
        float a0 = bf2f(gxeT[((size_t)t*1536 + gcol)*32 + b]);
        const short* ex = encxT + ((size_t)gcol<<5) + b;
#pragma unroll 4
        for (int s=0; s<128; ++s)
          a0 += alphaL[s*32+b] * bf2f(ex[(size_t)s*49152]);
        gxL[gcI][b] = a0;
      }
      __syncthreads();
      if (tid < 128){
        int hc = tid >> 5, b = tid & 31;
        int hcol = j*4 + hc;
        float gz = accL[0][hc][b]+accL[1][hc][b]+accL[2][hc][b]+accL[3][hc][b];
        float gr = accL[0][4+hc][b]+accL[1][4+hc][b]+accL[2][4+hc][b]+accL[3][4+hc][b];
        float gh = accL[0][8+hc][b]+accL[1][8+hc][b]+accL[2][8+hc][b]+accL[3][8+hc][b];
        gz += brd[hcol]; gr += brd[512+hcol]; gh += brd[1024+hcol];
        float z = sig_p(gxL[hc][b] + gz);
        float r = sig_p(gxL[4+hc][b] + gr);
        float hcand = tanhf(gxL[8+hc][b] + r*gh);
        float hp = hTd[cur*16384 + hcol*32 + b];
        float hn = z*hp + (1.f-z)*hcand;
        hTd[nxt*16384 + hcol*32 + b] = hn;
        hrowd[nxt*16384 + b*512 + hcol] = hn;
        decT[((size_t)t*512 + hcol)*32 + b] = f2bf(hn);
      }
      __syncthreads();
      if (tid == 0){ __threadfence(); atomicAdd(hcnt,1u); }
    }
  } else {
    // ---- attention workgroup, one batch b ----
    const int b = wg - 128;
    u32 wa[64];
    {
      const u32* wp = (const u32*)(Wa + (size_t)(tid&127)*512 + (tid>>7)*128);
#pragma unroll
      for (int i=0;i<64;++i) wa[i] = wp[i];
    }
    u32 ue[16];
    {
      int s = tid & 127, aq = tid >> 7;
      const u32* up = (const u32*)(Uenc + ((size_t)(s*32 + b))*128 + aq*32);
#pragma unroll
      for (int i=0;i<16;++i) ue[i] = up[i];
    }
    if (tid < 128) vL[tid] = Va[tid];

    for (int t=0; t<128; ++t){
      if (tid == 0) spin_ge(hcnt, 128u*(u32)t);
      __syncthreads();
      const int cur = t & 1;
      hs[tid] = hTd[cur*16384 + tid*32 + b];
      __syncthreads();
      // wh = h @ W_a^T  (k split 4-way)
      {
        int a = tid & 127, kq2 = tid >> 7;
        float p = 0.f;
        const float* hp2 = &hs[kq2*128];
#pragma unroll 8
        for (int i=0;i<64;++i){
          u32 w2 = wa[i];
          float2 h2 = *(const float2*)(hp2 + 2*i);
          p += bf2f((short)(w2 & 0xffff))*h2.x + bf2f((short)(w2 >> 16))*h2.y;
        }
        whp[a*5 + kq2] = p;
      }
      __syncthreads();
      if (tid < 128) whv[tid] = whp[tid*5]+whp[tid*5+1]+whp[tid*5+2]+whp[tid*5+3];
      __syncthreads();
      // score_s = sum_a tanh(wh_a + Uenc) * v_a  (a split 4-way)
      {
        int s = tid & 127, aq = tid >> 7;
        float p = 0.f;
#pragma unroll 4
        for (int i=0;i<16;++i){
          u32 u2 = ue[i];
          int a0 = aq*32 + 2*i;
          p += tanh_fast(whv[a0]   + bf2f((short)(u2 & 0xffff))) * vL[a0];
          p += tanh_fast(whv[a0+1] + bf2f((short)(u2 >> 16)))    * vL[a0+1];
        }
        scp[s*5 + aq] = p;
      }
      __syncthreads();
      if (tid < 128) sc[tid] = scp[tid*5]+scp[tid*5+1]+scp[tid*5+2]+scp[tid*5+3];
      __syncthreads();
      float ev = 0.f;
      if (tid < 128){
        float v = sc[tid], mx = v;
#pragma unroll
        for (int d2=32; d2; d2>>=1) mx = fmaxf(mx, __shfl_xor(mx, d2));
        if ((tid & 63) == 0) red[tid>>6] = mx;
      }
      __syncthreads();
      if (tid < 128){
        float mx = fmaxf(red[0], red[1]);
        ev = __expf(sc[tid] - mx);
        float sm = ev;
#pragma unroll
        for (int d2=32; d2; d2>>=1) sm += __shfl_xor(sm, d2);
        if ((tid & 63) == 0) red[2 + (tid>>6)] = sm;
      }
      __syncthreads();
      if (tid < 128) alphaT[tid*32 + b] = ev / (red[2] + red[3]);
      __syncthreads();
      if (tid == 0){ __threadfence(); atomicAdd(acnt,1u); }
    }
  }
}

// ---------------- softmax finish ----------------
__global__ void rowsum_inv(const float* __restrict__ psum, float* __restrict__ inv, int rows, int w){
  int r = blockIdx.x*256 + threadIdx.x;
  if (r < rows){
    float s = 0.f;
    const float* p = psum + (size_t)r*w;
    for (int i=0;i<w;++i) s += p[i];
    inv[r] = 1.f/s;
  }
}

__global__ void scale_rows(float* __restrict__ out, const float* __restrict__ inv, int ncols){
  int r = blockIdx.x;
  float v = inv[r];
  float* p = out + (size_t)r*ncols;
  for (int i = threadIdx.x; i < ncols; i += 256) p[i] *= v;
}

// ---------------- host ----------------
extern "C" void kernel_launch(void* const* d_in, const int* in_sizes, int n_in,
                              void* d_out, int out_size, void* d_ws, size_t ws_size,
                              hipStream_t stream)
{
  const int*   tokens=(const int*)  d_in[0];
  const float* emb  =(const float*)d_in[1];
  const float* Wx_f =(const float*)d_in[2];
  const float* Wh_f =(const float*)d_in[3];
  const float* bi_f =(const float*)d_in[4];
  const float* br_f =(const float*)d_in[5];
  const float* Wx_b =(const float*)d_in[6];
  const float* Wh_b =(const float*)d_in[7];
  const float* bi_b =(const float*)d_in[8];
  const float* br_b =(const float*)d_in[9];
  const float* W_a  =(const float*)d_in[10];
  const float* U_a  =(const float*)d_in[11];
  const float* V_a  =(const float*)d_in[12];
  const float* Wx_d =(const float*)d_in[13];
  const float* Wh_d =(const float*)d_in[14];
  const float* bi_d =(const float*)d_in[15];
  const float* br_d =(const float*)d_in[16];
  const float* Wo   =(const float*)d_in[17];
  const float* bo   =(const float*)d_in[18];

  const int NV = 32001, NVP = 32128, NCB = 251;

  char* base = (char*)d_ws; size_t off = 0;
  auto alloc = [&](size_t bytes)->char*{
    off = (off + 255) & ~(size_t)255;
    char* p = base + off; off += bytes; return p;
  };
  u32*   cnts   = (u32*)  alloc(256);                       // [0]=enc [1]=hcnt [2]=acnt
  short* X      = (short*)alloc((size_t)4096*256*2);
  short* WxfT   = (short*)alloc((size_t)1536*256*2);
  short* WxbT   = (short*)alloc((size_t)1536*256*2);
  short* WhfT   = (short*)alloc((size_t)1536*512*2);
  short* WhbT   = (short*)alloc((size_t)1536*512*2);
  short* WhdT   = (short*)alloc((size_t)1536*512*2);
  short* WxeT   = (short*)alloc((size_t)1536*1024*2);
  short* WxcT   = (short*)alloc((size_t)1536*1024*2);
  short* WoT    = (short*)alloc((size_t)NVP*512*2);
  short* UaB    = (short*)alloc((size_t)128*1024*2);
  short* WaB    = (short*)alloc((size_t)128*512*2);
  short* gxfT   = (short*)alloc((size_t)128*1536*32*2);
  short* gxbT   = (short*)alloc((size_t)128*1536*32*2);
  short* encT   = (short*)alloc((size_t)128*1024*32*2);
  short* encRow = (short*)alloc((size_t)4096*1024*2);
  short* Uenc   = (short*)alloc((size_t)4096*128*2);
  short* gxeT   = (short*)alloc((size_t)128*1536*32*2);
  short* encxT  = (short*)alloc((size_t)128*1536*32*2);
  short* decT   = (short*)alloc((size_t)128*512*32*2);
  short* decRow = (short*)alloc((size_t)4096*512*2);
  float* hT_e   = (float*)alloc((size_t)2*2*512*32*4);
  float* hrow_e = (float*)alloc((size_t)2*2*32*512*4);
  float* hT_d   = (float*)alloc((size_t)2*512*32*4);
  float* hrow_d = (float*)alloc((size_t)2*32*512*4);
  float* alphaT = (float*)alloc((size_t)128*32*4);
  float* psum   = (float*)alloc((size_t)4096*2*NCB*4);
  float* invr   = (float*)alloc((size_t)4096*4);

  hipMemsetAsync(cnts, 0, 256, stream);
  hipMemsetAsync(hT_e,   0, (size_t)2*2*512*32*4, stream);
  hipMemsetAsync(hrow_e, 0, (size_t)2*2*32*512*4, stream);

  // weight conversions (all BT = [N][K] bf16 via transpose; WhT also [N][K])
  tconv<<<dim3(1536/32,256/32),dim3(32,8),0,stream>>>(Wx_f, WxfT, 256, 1536, 1536);
  tconv<<<dim3(1536/32,256/32),dim3(32,8),0,stream>>>(Wx_b, WxbT, 256, 1536, 1536);
  tconv<<<dim3(1536/32,512/32),dim3(32,8),0,stream>>>(Wh_f, WhfT, 512, 1536, 1536);
  tconv<<<dim3(1536/32,512/32),dim3(32,8),0,stream>>>(Wh_b, WhbT, 512, 1536, 1536);
  tconv<<<dim3(1536/32,512/32),dim3(32,8),0,stream>>>(Wh_d, WhdT, 512, 1536, 1536);
  tconv<<<dim3(1536/32,1024/32),dim3(32,8),0,stream>>>(Wx_d,             WxeT, 1024, 1536, 1536);
  tconv<<<dim3(1536/32,1024/32),dim3(32,8),0,stream>>>(Wx_d+(size_t)1024*1536, WxcT, 1024, 1536, 1536);
  tconv<<<dim3(NVP/32,512/32),dim3(32,8),0,stream>>>(Wo, WoT, 512, NV, NVP);
  cvt1d<<<(128*512+255)/256,256,0,stream>>>(W_a, WaB, 128*512);
  cvt1d<<<(128*1024+255)/256,256,0,stream>>>(U_a, UaB, 128*1024);

  embed_k<<<4096,256,0,stream>>>(tokens, emb, X);

  gemm_k<1><<<dim3(12,32),256,0,stream>>>(X, WxfT, bi_f, gxfT, nullptr, 1536, 256, 1536);
  gemm_k<1><<<dim3(12,32),256,0,stream>>>(X, WxbT, bi_b, gxbT, nullptr, 1536, 256, 1536);

  enc_scan<<<64,384,0,stream>>>(gxfT, gxbT, WhfT, WhbT, br_f, br_b, hT_e, hrow_e, encT, &cnts[0]);

  btrans<<<dim3(1024/32,128),dim3(32,8),0,stream>>>(encT, encRow, 1024);

  gemm_k<3><<<dim3(1,32),256,0,stream>>>(encRow, UaB, nullptr, Uenc, nullptr, 128, 1024, 128);
  gemm_k<1><<<dim3(12,32),256,0,stream>>>(encRow, WxeT, bi_d, gxeT, nullptr, 1536, 1024, 1536);
  gemm_k<1><<<dim3(12,32),256,0,stream>>>(encRow, WxcT, nullptr, encxT, nullptr, 1536, 1024, 1536);

  // decoder h0 = backward final h (dir=1, buf=0)
  hipMemcpyAsync(hT_d,   hT_e   + 32768, (size_t)512*32*4, hipMemcpyDeviceToDevice, stream);
  hipMemcpyAsync(hrow_d, hrow_e + 32768, (size_t)32*512*4, hipMemcpyDeviceToDevice, stream);

  dec_scan<<<160,512,0,stream>>>(gxeT, encxT, WhdT, br_d, WaB, Uenc, V_a,
                                 hT_d, hrow_d, alphaT, decT, &cnts[1], &cnts[2]);

  btrans<<<dim3(512/32,128),dim3(32,8),0,stream>>>(decT, decRow, 512);

  gemm_k<2><<<dim3(NCB,32),256,0,stream>>>(decRow, WoT, bo, d_out, psum, NV, 512, NV);

  rowsum_inv<<<16,256,0,stream>>>(psum, invr, 4096, 2*NCB);
  scale_rows<<<4096,256,0,stream>>>((float*)d_out, invr, NV);
}

// Round 2
// 5646.846 us; speedup vs baseline: 1.2203x; 1.2203x over previous
//
#include <hip/hip_runtime.h>
#include <stdint.h>

typedef unsigned int u32;
typedef __attribute__((ext_vector_type(8))) short bf16x8;
typedef __attribute__((ext_vector_type(4))) float f32x4;
typedef __attribute__((ext_vector_type(4))) int i32x4;
typedef __attribute__((ext_vector_type(2))) int i32x2;

#define DEV static __device__ __forceinline__

DEV short f2bf(float f){ u32 u=__float_as_uint(f); return (short)((u + 0x7fffu + ((u>>16)&1u))>>16); }
DEV float bf2f(short s){ return __uint_as_float(((u32)(unsigned short)s)<<16); }
DEV float sig_p(float x){ return 1.f/(1.f+expf(-x)); }
DEV float tanh_fast(float x){ float e=__expf(2.f*x); return 1.f-2.f/(e+1.f); }
DEV void spin_ge(u32* c, u32 tgt){
  while(__hip_atomic_load(c,__ATOMIC_RELAXED,__HIP_MEMORY_SCOPE_AGENT)<tgt) __builtin_amdgcn_s_sleep(2);
  __threadfence();
}
DEV u32 radd(u32* c){ return __hip_atomic_fetch_add(c, 1u, __ATOMIC_ACQ_REL, __HIP_MEMORY_SCOPE_AGENT); }
DEV void est(u32* e, u32 v){ __hip_atomic_store(e, v, __ATOMIC_RELEASE, __HIP_MEMORY_SCOPE_AGENT); }

// ---------------- convert / transpose kernels ----------------

__global__ void cvt1d(const float* __restrict__ in, short* __restrict__ out, int n){
  int i = blockIdx.x*256 + threadIdx.x;
  if (i < n) out[i] = f2bf(in[i]);
}

// in f32 [R][C] (row stride C) -> out bf16 [Cpad][R], rows >= C zero-filled
__global__ void tconv(const float* __restrict__ in, short* __restrict__ out, int R, int C, int Cpad){
  __shared__ float t[32][33];
  int tx = threadIdx.x, ty = threadIdx.y;
  int c0 = blockIdx.x*32, r0 = blockIdx.y*32;
#pragma unroll
  for (int j=0;j<4;++j){
    int r = r0 + ty + 8*j, c = c0 + tx;
    t[ty+8*j][tx] = (c < C) ? in[(size_t)r*C + c] : 0.f;
  }
  __syncthreads();
#pragma unroll
  for (int j=0;j<4;++j){
    int oc = c0 + ty + 8*j;          // out row (= original col)
    out[(size_t)oc*R + r0 + tx] = f2bf(t[tx][ty+8*j]);
  }
}

// batched transpose: in bf16 [NB][Dd][32] -> out bf16 [NB*32][Dd]
__global__ void btrans(const short* __restrict__ in, short* __restrict__ out, int Dd){
  __shared__ short t[32][33];
  int tx = threadIdx.x, ty = threadIdx.y;
  int d0 = blockIdx.x*32, s = blockIdx.y;
#pragma unroll
  for (int j=0;j<4;++j)
    t[ty+8*j][tx] = in[((size_t)s*Dd + d0 + ty + 8*j)*32 + tx];
  __syncthreads();
#pragma unroll
  for (int j=0;j<4;++j)
    out[((size_t)(s*32 + ty + 8*j))*Dd + d0 + tx] = t[tx][ty+8*j];
}

// embedding gather: X[(s*32+b)][d] = bf16(emb[tok[b][s]][d])
__global__ void embed_k(const int* __restrict__ tok, const float* __restrict__ emb, short* __restrict__ X){
  int row = blockIdx.x;               // (s,b)
  int s = row >> 5, b = row & 31;
  int tv = tok[b*128 + s];
  X[(size_t)row*256 + threadIdx.x] = f2bf(emb[(size_t)tv*256 + threadIdx.x]);
}

// ---------------- MFMA GEMM  C = A[M,K] * B (B given as BT[Npad][K]) ----------------
// MODE 1: out bf16 T-layout [s][Ntot][32], + bias
// MODE 2: out f32 d_out exp(logit+bias) with (s,b)->(b,s) row remap + psum partials
// MODE 3: out bf16 row-major [M][Nreal], (+bias if non-null)
// MODE 4: out bf16 [col][32 b][128 s]   (for ENCX)
template<int MODE>
__global__ __launch_bounds__(256) void gemm_k(
  const short* __restrict__ A, const short* __restrict__ BT,
  const float* __restrict__ bias, void* __restrict__ outp,
  float* __restrict__ psum, int Nreal, int K, int Ntot)
{
  const int m0 = blockIdx.y * 128, n0 = blockIdx.x * 128;
  const int tid = threadIdx.x, l = tid & 63, wv = tid >> 6;
  const int wm = wv >> 1, wn = wv & 1;
  __shared__ __align__(16) short As[128*64];
  __shared__ __align__(16) short Bs[128*64];
  f32x4 acc[4][4];
#pragma unroll
  for (int i=0;i<4;++i)
#pragma unroll
    for (int j=0;j<4;++j) acc[i][j] = (f32x4){0.f,0.f,0.f,0.f};

  const int nkb = K >> 6;
  for (int kb=0; kb<nkb; ++kb){
#pragma unroll
    for (int i=0;i<4;++i){
      int si = tid + i*256;
      int row = si >> 3, seg = si & 7;
      u32 off = (u32)(row*128 + seg*16) ^ (u32)((row&7)<<4);
      *(i32x4*)((char*)As + off) = *(const i32x4*)(A + (size_t)(m0+row)*K + kb*64 + seg*8);
      *(i32x4*)((char*)Bs + off) = *(const i32x4*)(BT + (size_t)(n0+row)*K + kb*64 + seg*8);
    }
    __syncthreads();
#pragma unroll
    for (int kt=0; kt<2; ++kt){
      bf16x8 af[4], bfv[4];
      int seg = kt*4 + (l>>4);
#pragma unroll
      for (int f=0; f<4; ++f){
        int ra = wm*64 + f*16 + (l&15);
        af[f]  = *(const bf16x8*)((char*)As + (((u32)(ra*128 + seg*16)) ^ ((u32)(ra&7)<<4)));
        int rb = wn*64 + f*16 + (l&15);
        bfv[f] = *(const bf16x8*)((char*)Bs + (((u32)(rb*128 + seg*16)) ^ ((u32)(rb&7)<<4)));
      }
#pragma unroll
      for (int mf=0; mf<4; ++mf)
#pragma unroll
        for (int nf=0; nf<4; ++nf)
          acc[mf][nf] = __builtin_amdgcn_mfma_f32_16x16x32_bf16(af[mf], bfv[nf], acc[mf][nf], 0,0,0);
    }
    __syncthreads();
  }

  if (MODE == 1){
    short* oT = (short*)outp;
#pragma unroll
    for (int mf=0; mf<4; ++mf){
      int r0 = m0 + wm*64 + mf*16 + ((l>>4)<<2);
      int s = r0 >> 5, b0 = r0 & 31;
#pragma unroll
      for (int nf=0; nf<4; ++nf){
        int col = n0 + wn*64 + nf*16 + (l&15);
        float bv = bias ? bias[col] : 0.f;
        short tmp[4];
#pragma unroll
        for (int j=0;j<4;++j) tmp[j] = f2bf(acc[mf][nf][j] + bv);
        *(i32x2*)(oT + ((size_t)s*Ntot + col)*32 + b0) = *(i32x2*)tmp;
      }
    }
  } else if (MODE == 3){
    short* o = (short*)outp;
#pragma unroll
    for (int mf=0; mf<4; ++mf){
      int r0 = m0 + wm*64 + mf*16 + ((l>>4)<<2);
#pragma unroll
      for (int nf=0; nf<4; ++nf){
        int col = n0 + wn*64 + nf*16 + (l&15);
        if (col < Nreal){
          float bv = bias ? bias[col] : 0.f;
#pragma unroll
          for (int j=0;j<4;++j) o[(size_t)(r0+j)*Nreal + col] = f2bf(acc[mf][nf][j] + bv);
        }
      }
    }
  } else if (MODE == 4){
    short* o = (short*)outp;
#pragma unroll
    for (int mf=0; mf<4; ++mf){
      int r0 = m0 + wm*64 + mf*16 + ((l>>4)<<2);
      int s = r0 >> 5, b0 = r0 & 31;
#pragma unroll
      for (int nf=0; nf<4; ++nf){
        int col = n0 + wn*64 + nf*16 + (l&15);
#pragma unroll
        for (int j=0;j<4;++j)
          o[((size_t)col*32 + b0 + j)*128 + s] = f2bf(acc[mf][nf][j]);
      }
    }
  } else { // MODE 2
    float* o = (float*)outp;
    int ncb = gridDim.x;
    float rs[4][4];
#pragma unroll
    for (int i=0;i<4;++i)
#pragma unroll
      for (int j=0;j<4;++j) rs[i][j]=0.f;
#pragma unroll
    for (int mf=0; mf<4; ++mf){
      int r0 = m0 + wm*64 + mf*16 + ((l>>4)<<2);
      int s = r0 >> 5, b0 = r0 & 31;
#pragma unroll
      for (int nf=0; nf<4; ++nf){
        int col = n0 + wn*64 + nf*16 + (l&15);
        if (col < Nreal){
          float bv = bias[col];
#pragma unroll
          for (int j=0;j<4;++j){
            float e = __expf(acc[mf][nf][j] + bv);
            o[(size_t)((b0+j)*128 + s)*Nreal + col] = e;
            rs[mf][j] += e;
          }
        }
      }
    }
#pragma unroll
    for (int mf=0; mf<4; ++mf)
#pragma unroll
      for (int j=0;j<4;++j){
        float v = rs[mf][j];
        v += __shfl_xor(v,1); v += __shfl_xor(v,2); v += __shfl_xor(v,4); v += __shfl_xor(v,8);
        if ((l&15)==0){
          int r = m0 + wm*64 + mf*16 + ((l>>4)<<2) + j;
          int orow = (r&31)*128 + (r>>5);
          psum[(size_t)orow*(2*ncb) + blockIdx.x*2 + wn] = v;
        }
      }
  }
}

// ---------------- encoder scan (64 WGs x 512 thr, epoch barrier) ----------------
// WG: dir = wg>>5, ws = wg&31, owns 16 h-cols (c0 = ws*16) -> 48 gate cols.
// Wh slice in LDS (swizzled); h state in global bf16 [dir][2buf][32 b][512 k].
__global__ __launch_bounds__(512,2) void enc_scan(
  const short* __restrict__ gxfT, const short* __restrict__ gxbT,
  const short* __restrict__ WhfT, const short* __restrict__ WhbT,
  const float* __restrict__ brf, const float* __restrict__ brb,
  float* __restrict__ hT, short* __restrict__ hrowB,
  short* __restrict__ encT, u32* __restrict__ cnt, u32* __restrict__ epoch)
{
  extern __shared__ char dsm[];
  short* wh = (short*)dsm;                       // [48 c][512 k] swizzled, 49152 B
  __shared__ float accL[48][33];
  const int tid = threadIdx.x, wg = blockIdx.x;
  const int dir = wg >> 5, ws = wg & 31, c0 = ws*16;
  const short* gxT = dir ? gxbT : gxfT;
  const short* WT  = dir ? WhbT : WhfT;
  const float* br  = dir ? brb  : brf;
  float* hTd    = hT    + dir*32768;             // [2][512][32] f32
  short* hrowBd = hrowB + dir*32768;             // [2][32][512] bf16
  const int l = tid & 63, wv = tid >> 6;

  // load Wh slice into LDS (swizzled, 16B units)
  for (int u = tid; u < 3072; u += 512){
    int c = u >> 6, kseg = u & 63;
    int gc = (c>>4)*512 + c0 + (c&15);
    i32x4 v = *(const i32x4*)(WT + (size_t)gc*512 + kseg*8);
    *(i32x4*)(dsm + (((u32)(c*1024 + kseg*16)) ^ ((u32)(c&7)<<4))) = v;
  }
  __syncthreads();

  for (int t=0; t<128; ++t){
    const int s = dir ? (127-t) : t;
    const int cur = t & 1, nxt = cur ^ 1;
    if (t > 0){
      if (tid == 0) spin_ge(epoch, (u32)t);
      __syncthreads();
    }
    // gh = h @ Wh : waves 0..5, roles (m in 2) x (n in 3), K=512
    if (wv < 6){
      const int m = wv & 1, n = wv >> 1;
      const short* ap = hrowBd + (size_t)(cur*32 + m*16 + (l&15))*512 + ((l>>4)<<3);
      f32x4 acc = (f32x4){0.f,0.f,0.f,0.f};
#pragma unroll
      for (int kt=0; kt<16; ++kt){
        bf16x8 af = *(const bf16x8*)(ap + kt*32);
        int c = n*16 + (l&15);
        int kseg = kt*4 + (l>>4);
        bf16x8 bf = *(const bf16x8*)(dsm + (((u32)(c*1024 + kseg*16)) ^ ((u32)(c&7)<<4)));
        acc = __builtin_amdgcn_mfma_f32_16x16x32_bf16(af, bf, acc, 0,0,0);
      }
      *(f32x4*)&accL[n*16 + (l&15)][m*16 + ((l>>4)<<2)] = acc;
    }
    __syncthreads();
    // gates: 512 outputs = 16 h-cols x 32 b
    {
      int hc = tid >> 5, b = tid & 31;
      int hcol = c0 + hc;
      size_t gb = ((size_t)s*1536 + hcol)*32 + b;
      float xz = bf2f(gxT[gb]);
      float xr = bf2f(gxT[gb + 512*32]);
      float xh = bf2f(gxT[gb + 1024*32]);
      float gz = accL[hc][b]      + br[hcol];
      float gr = accL[16+hc][b]   + br[512+hcol];
      float gh = accL[32+hc][b]   + br[1024+hcol];
      float z = sig_p(xz + gz);
      float r = sig_p(xr + gr);
      float hcand = tanhf(xh + r*gh);
      float hp = hTd[cur*16384 + hcol*32 + b];
      float hn = z*hp + (1.f-z)*hcand;
      hTd[nxt*16384 + hcol*32 + b] = hn;
      hrowBd[nxt*16384 + b*512 + hcol] = f2bf(hn);
      encT[((size_t)s*1024 + dir*512 + hcol)*32 + b] = f2bf(hn);
    }
    __syncthreads();
    if (tid == 0){
      u32 old = radd(cnt);
      if (old == 64u*(u32)(t+1) - 1u) est(epoch, (u32)(t+1));
    }
  }
}

// ---------------- decoder init: h0 = backward-final encoder h ----------------
__global__ void dec_init(const float* __restrict__ src, float* __restrict__ hT_d,
                         float* __restrict__ hrowF, short* __restrict__ hrowB){
  int i = blockIdx.x*256 + threadIdx.x;   // 16384 = 512 hcol x 32 b
  int hcol = i >> 5, b = i & 31;
  float v = src[i];
  hT_d[i] = v;
  hrowF[b*512 + hcol] = v;
  hrowB[b*512 + hcol] = f2bf(v);
}

// ---------------- decoder scan (96 WGs x 512 thr) ----------------
// wg 0..63  : gates WG, owns 8 h-cols (j*8..) -> 24 gate cols; Wh slice in LDS
// wg 64..95 : attention WG, one batch b; Wa/Uenc slices in registers
__global__ __launch_bounds__(512,2) void dec_scan(
  const short* __restrict__ gxeT, const short* __restrict__ encx,
  const short* __restrict__ WhdT, const float* __restrict__ brd,
  const short* __restrict__ Wa, const short* __restrict__ Uenc, const float* __restrict__ Va,
  float* __restrict__ hTd, float* __restrict__ hrowF, short* __restrict__ hrowB,
  float* __restrict__ alphaT, short* __restrict__ decT,
  u32* __restrict__ hcnt, u32* __restrict__ eph,
  u32* __restrict__ acnt, u32* __restrict__ epa)
{
  extern __shared__ char dsm[];                  // gates: Wh [32c][512k] swizzled 32768 B
  __shared__ float aL[4096];                     // alpha [128 s][32 b]
  __shared__ float accL[2][32][33];              // kh-partial gh [c][b]
  __shared__ float gxL[24][32];
  // attention statics
  __shared__ float hs[512];
  __shared__ float whp[128*5];
  __shared__ float whv[128];
  __shared__ float scp[128*5];
  __shared__ float sc[128];
  __shared__ float red[4];
  __shared__ float vL[128];

  const int tid = threadIdx.x, wg = blockIdx.x;
  const int l = tid & 63, wv = tid >> 6;

  if (wg < 64){
    // ---- gates WG j ----
    const int j = wg;
    // load Wh slice (24 real cols of 32) into LDS swizzled
    for (int u = tid; u < 1536; u += 512){
      int c = u >> 6, kseg = u & 63;
      int gc = (c>>3)*512 + j*8 + (c&7);
      i32x4 v = *(const i32x4*)(WhdT + (size_t)gc*512 + kseg*8);
      *(i32x4*)(dsm + (((u32)(c*1024 + kseg*16)) ^ ((u32)(c&7)<<4))) = v;
    }
    __syncthreads();
    const int m = wv & 1, n = (wv >> 1) & 1, kh = wv >> 2;   // 8 roles
    for (int t=0; t<128; ++t){
      const int cur = t & 1, nxt = cur ^ 1;
      if (t > 0){
        if (tid == 0) spin_ge(eph, (u32)t);
        __syncthreads();
      }
      // gh partial: M=32 b, N=32 cols (24 real), K-half per kh
      {
        const short* ap = hrowB + (size_t)(cur*32 + m*16 + (l&15))*512 + kh*256 + ((l>>4)<<3);
        f32x4 acc = (f32x4){0.f,0.f,0.f,0.f};
#pragma unroll
        for (int kt=0; kt<8; ++kt){
          bf16x8 af = *(const bf16x8*)(ap + kt*32);
          int c = n*16 + (l&15);
          int kseg = kh*32 + kt*4 + (l>>4);
          bf16x8 bf = *(const bf16x8*)(dsm + (((u32)(c*1024 + kseg*16)) ^ ((u32)(c&7)<<4)));
          acc = __builtin_amdgcn_mfma_f32_16x16x32_bf16(af, bf, acc, 0,0,0);
        }
        *(f32x4*)&accL[kh][n*16 + (l&15)][m*16 + ((l>>4)<<2)] = acc;
      }
      // wait for alpha_t, stage it
      if (tid == 0) spin_ge(epa, (u32)(t+1));
      __syncthreads();
#pragma unroll
      for (int i=0;i<8;++i){ int idx = tid + i*512; aL[idx] = alphaT[idx]; }
      __syncthreads();
      // gx = gxe (incl bi_d) + sum_s alpha[s][b] * ENCX[gcol][b][s]
      for (int p = tid; p < 768; p += 512){
        int c = p >> 5, b = p & 31;
        int gcol = (c>>3)*512 + j*8 + (c&7);
        float acc = bf2f(gxeT[((size_t)t*1536 + gcol)*32 + b]);
        const i32x4* ex = (const i32x4*)(encx + ((size_t)gcol*32 + b)*128);
#pragma unroll
        for (int i=0;i<16;++i){
          i32x4 v = ex[i];
#pragma unroll
          for (int q=0;q<4;++q){
            u32 w = (u32)v[q];
            acc += bf2f((short)(w & 0xffff)) * aL[(i*8 + q*2    )*32 + b];
            acc += bf2f((short)(w >> 16))    * aL[(i*8 + q*2 + 1)*32 + b];
          }
        }
        gxL[c][b] = acc;
      }
      __syncthreads();
      // pointwise: 8 h-cols x 32 b
      if (tid < 256){
        int hc = tid >> 5, b = tid & 31;
        int hcol = j*8 + hc;
        float gz = accL[0][hc][b]    + accL[1][hc][b]    + brd[hcol];
        float gr = accL[0][8+hc][b]  + accL[1][8+hc][b]  + brd[512+hcol];
        float gh = accL[0][16+hc][b] + accL[1][16+hc][b] + brd[1024+hcol];
        float z = sig_p(gxL[hc][b] + gz);
        float r = sig_p(gxL[8+hc][b] + gr);
        float hcand = tanhf(gxL[16+hc][b] + r*gh);
        float hp = hTd[cur*16384 + hcol*32 + b];
        float hn = z*hp + (1.f-z)*hcand;
        hTd[nxt*16384 + hcol*32 + b] = hn;
        hrowF[nxt*16384 + b*512 + hcol] = hn;
        hrowB[nxt*16384 + b*512 + hcol] = f2bf(hn);
        decT[((size_t)t*512 + hcol)*32 + b] = f2bf(hn);
      }
      __syncthreads();
      if (tid == 0){
        u32 old = radd(hcnt);
        if (old == 64u*(u32)(t+1) - 1u) est(eph, (u32)(t+1));
      }
    }
  } else {
    // ---- attention WG, batch b ----
    const int b = wg - 64;
    u32 wa[64];
    {
      const u32* wp = (const u32*)(Wa + (size_t)(tid&127)*512 + (tid>>7)*128);
#pragma unroll
      for (int i=0;i<64;++i) wa[i] = wp[i];
    }
    u32 ue[16];
    {
      int s = tid & 127;
      int aq = tid >> 7;
      const u32* up = (const u32*)(Uenc + ((size_t)(s*32 + b))*128 + aq*32);
#pragma unroll
      for (int i=0;i<16;++i) ue[i] = up[i];
    }
    if (tid < 128) vL[tid] = Va[tid];

    for (int t=0; t<128; ++t){
      if (t > 0){
        if (tid == 0) spin_ge(eph, (u32)t);
      }
      __syncthreads();
      const int cur = t & 1;
      hs[tid] = hrowF[cur*16384 + b*512 + tid];
      __syncthreads();
      // wh = h @ Wa^T  (k split 4-way)
      {
        int a = tid & 127, kq2 = tid >> 7;
        float p = 0.f;
        const float* hp2 = &hs[kq2*128];
#pragma unroll 8
        for (int i=0;i<64;++i){
          u32 w2 = wa[i];
          float2 h2 = *(const float2*)(hp2 + 2*i);
          p += bf2f((short)(w2 & 0xffff))*h2.x + bf2f((short)(w2 >> 16))*h2.y;
        }
        whp[a*5 + kq2] = p;
      }
      __syncthreads();
      if (tid < 128) whv[tid] = whp[tid*5]+whp[tid*5+1]+whp[tid*5+2]+whp[tid*5+3];
      __syncthreads();
      // score_s = sum_a tanh(wh_a + Uenc) * v_a  (a split 4-way)
      {
        int s = tid & 127, aq = tid >> 7;
        float p = 0.f;
#pragma unroll 4
        for (int i=0;i<16;++i){
          u32 u2 = ue[i];
          int a0 = aq*32 + 2*i;
          p += tanh_fast(whv[a0]   + bf2f((short)(u2 & 0xffff))) * vL[a0];
          p += tanh_fast(whv[a0+1] + bf2f((short)(u2 >> 16)))    * vL[a0+1];
        }
        scp[s*5 + aq] = p;
      }
      __syncthreads();
      if (tid < 128) sc[tid] = scp[tid*5]+scp[tid*5+1]+scp[tid*5+2]+scp[tid*5+3];
      __syncthreads();
      float ev = 0.f;
      if (tid < 128){
        float v = sc[tid], mx = v;
#pragma unroll
        for (int d2=32; d2; d2>>=1) mx = fmaxf(mx, __shfl_xor(mx, d2));
        if ((tid & 63) == 0) red[tid>>6] = mx;
      }
      __syncthreads();
      if (tid < 128){
        float mx = fmaxf(red[0], red[1]);
        ev = __expf(sc[tid] - mx);
        float sm = ev;
#pragma unroll
        for (int d2=32; d2; d2>>=1) sm += __shfl_xor(sm, d2);
        if ((tid & 63) == 0) red[2 + (tid>>6)] = sm;
      }
      __syncthreads();
      if (tid < 128) alphaT[tid*32 + b] = ev / (red[2] + red[3]);
      __syncthreads();
      if (tid == 0){
        u32 old = radd(acnt);
        if (old == 32u*(u32)(t+1) - 1u) est(epa, (u32)(t+1));
      }
    }
  }
}

// ---------------- softmax finish: per-row sum(psum) then scale ----------------
__global__ void scale_rows(float* __restrict__ out, const float* __restrict__ psum,
                           int ncols, int w){
  int r = blockIdx.x;
  __shared__ float ssum[256];
  float s = 0.f;
  for (int i = threadIdx.x; i < w; i += 256) s += psum[(size_t)r*w + i];
  ssum[threadIdx.x] = s; __syncthreads();
  for (int d = 128; d; d >>= 1){
    if (threadIdx.x < d) ssum[threadIdx.x] += ssum[threadIdx.x + d];
    __syncthreads();
  }
  float v = 1.f/ssum[0];
  float* p = out + (size_t)r*ncols;
  for (int i = threadIdx.x; i < ncols; i += 256) p[i] *= v;
}

// ---------------- host ----------------
extern "C" void kernel_launch(void* const* d_in, const int* in_sizes, int n_in,
                              void* d_out, int out_size, void* d_ws, size_t ws_size,
                              hipStream_t stream)
{
  const int*   tokens=(const int*)  d_in[0];
  const float* emb  =(const float*)d_in[1];
  const float* Wx_f =(const float*)d_in[2];
  const float* Wh_f =(const float*)d_in[3];
  const float* bi_f =(const float*)d_in[4];
  const float* br_f =(const float*)d_in[5];
  const float* Wx_b =(const float*)d_in[6];
  const float* Wh_b =(const float*)d_in[7];
  const float* bi_b =(const float*)d_in[8];
  const float* br_b =(const float*)d_in[9];
  const float* W_a  =(const float*)d_in[10];
  const float* U_a  =(const float*)d_in[11];
  const float* V_a  =(const float*)d_in[12];
  const float* Wx_d =(const float*)d_in[13];
  const float* Wh_d =(const float*)d_in[14];
  const float* bi_d =(const float*)d_in[15];
  const float* br_d =(const float*)d_in[16];
  const float* Wo   =(const float*)d_in[17];
  const float* bo   =(const float*)d_in[18];

  const int NV = 32001, NVP = 32128, NCB = 251;

  char* base = (char*)d_ws; size_t off = 0;
  auto alloc = [&](size_t bytes)->char*{
    off = (off + 255) & ~(size_t)255;
    char* p = base + off; off += bytes; return p;
  };
  u32*   cnts   = (u32*)  alloc(512);   // [0]=enc cnt,[16]=enc epoch,[32]=hcnt,[48]=eph,[64]=acnt,[80]=epa
  short* X      = (short*)alloc((size_t)4096*256*2);
  short* WxfT   = (short*)alloc((size_t)1536*256*2);
  short* WxbT   = (short*)alloc((size_t)1536*256*2);
  short* WhfT   = (short*)alloc((size_t)1536*512*2);
  short* WhbT   = (short*)alloc((size_t)1536*512*2);
  short* WhdT   = (short*)alloc((size_t)1536*512*2);
  short* WxeT   = (short*)alloc((size_t)1536*1024*2);
  short* WxcT   = (short*)alloc((size_t)1536*1024*2);
  short* WoT    = (short*)alloc((size_t)NVP*512*2);
  short* UaB    = (short*)alloc((size_t)128*1024*2);
  short* WaB    = (short*)alloc((size_t)128*512*2);
  short* gxfT   = (short*)alloc((size_t)128*1536*32*2);
  short* gxbT   = (short*)alloc((size_t)128*1536*32*2);
  short* encT   = (short*)alloc((size_t)128*1024*32*2);
  short* encRow = (short*)alloc((size_t)4096*1024*2);
  short* Uenc   = (short*)alloc((size_t)4096*128*2);
  short* gxeT   = (short*)alloc((size_t)128*1536*32*2);
  short* encx   = (short*)alloc((size_t)1536*32*128*2);   // [gcol][b][s]
  short* decT   = (short*)alloc((size_t)128*512*32*2);
  short* decRow = (short*)alloc((size_t)4096*512*2);
  float* hT_e   = (float*)alloc((size_t)2*2*512*32*4);
  short* hrowB_e= (short*)alloc((size_t)2*2*32*512*2);
  float* hT_d   = (float*)alloc((size_t)2*512*32*4);
  float* hrowF_d= (float*)alloc((size_t)2*32*512*4);
  short* hrowB_d= (short*)alloc((size_t)2*32*512*2);
  float* alphaT = (float*)alloc((size_t)128*32*4);
  float* psum   = (float*)alloc((size_t)4096*2*NCB*4);

  hipMemsetAsync(cnts, 0, 512, stream);
  hipMemsetAsync(hT_e, 0, (size_t)2*2*512*32*4, stream);
  hipMemsetAsync(hrowB_e, 0, (size_t)2*2*32*512*2, stream);

  // weight conversions (all BT = [N][K] bf16 via transpose)
  tconv<<<dim3(1536/32,256/32),dim3(32,8),0,stream>>>(Wx_f, WxfT, 256, 1536, 1536);
  tconv<<<dim3(1536/32,256/32),dim3(32,8),0,stream>>>(Wx_b, WxbT, 256, 1536, 1536);
  tconv<<<dim3(1536/32,512/32),dim3(32,8),0,stream>>>(Wh_f, WhfT, 512, 1536, 1536);
  tconv<<<dim3(1536/32,512/32),dim3(32,8),0,stream>>>(Wh_b, WhbT, 512, 1536, 1536);
  tconv<<<dim3(1536/32,512/32),dim3(32,8),0,stream>>>(Wh_d, WhdT, 512, 1536, 1536);
  tconv<<<dim3(1536/32,1024/32),dim3(32,8),0,stream>>>(Wx_d,                    WxeT, 1024, 1536, 1536);
  tconv<<<dim3(1536/32,1024/32),dim3(32,8),0,stream>>>(Wx_d+(size_t)1024*1536,  WxcT, 1024, 1536, 1536);
  tconv<<<dim3(NVP/32,512/32),dim3(32,8),0,stream>>>(Wo, WoT, 512, NV, NVP);
  cvt1d<<<(128*512+255)/256,256,0,stream>>>(W_a, WaB, 128*512);
  cvt1d<<<(128*1024+255)/256,256,0,stream>>>(U_a, UaB, 128*1024);

  embed_k<<<4096,256,0,stream>>>(tokens, emb, X);

  gemm_k<1><<<dim3(12,32),256,0,stream>>>(X, WxfT, bi_f, gxfT, nullptr, 1536, 256, 1536);
  gemm_k<1><<<dim3(12,32),256,0,stream>>>(X, WxbT, bi_b, gxbT, nullptr, 1536, 256, 1536);

  enc_scan<<<64,512,49152,stream>>>(gxfT, gxbT, WhfT, WhbT, br_f, br_b,
                                    hT_e, hrowB_e, encT, &cnts[0], &cnts[16]);

  btrans<<<dim3(1024/32,128),dim3(32,8),0,stream>>>(encT, encRow, 1024);

  gemm_k<3><<<dim3(1,32),256,0,stream>>>(encRow, UaB, nullptr, Uenc, nullptr, 128, 1024, 128);
  gemm_k<1><<<dim3(12,32),256,0,stream>>>(encRow, WxeT, bi_d, gxeT, nullptr, 1536, 1024, 1536);
  gemm_k<4><<<dim3(12,32),256,0,stream>>>(encRow, WxcT, nullptr, encx, nullptr, 1536, 1024, 1536);

  // decoder h0 = backward final h (dir=1, buf0)
  dec_init<<<64,256,0,stream>>>(hT_e + 32768, hT_d, hrowF_d, hrowB_d);

  dec_scan<<<96,512,32768,stream>>>(gxeT, encx, WhdT, br_d, WaB, Uenc, V_a,
                                    hT_d, hrowF_d, hrowB_d, alphaT, decT,
                                    &cnts[32], &cnts[48], &cnts[64], &cnts[80]);

  btrans<<<dim3(512/32,128),dim3(32,8),0,stream>>>(decT, decRow, 512);

  gemm_k<2><<<dim3(NCB,32),256,0,stream>>>(decRow, WoT, bo, d_out, psum, NV, 512, NV);

  scale_rows<<<4096,256,0,stream>>>((float*)d_out, psum, NV, 2*NCB);
}

// Round 3
// 5195.489 us; speedup vs baseline: 1.3263x; 1.0869x over previous
//
#include <hip/hip_runtime.h>
#include <stdint.h>

typedef unsigned int u32;
typedef unsigned long long u64;
typedef __attribute__((ext_vector_type(8))) short bf16x8;
typedef __attribute__((ext_vector_type(4))) float f32x4;
typedef __attribute__((ext_vector_type(4))) int i32x4;
typedef __attribute__((ext_vector_type(2))) int i32x2;

#define DEV static __device__ __forceinline__

DEV short f2bf(float f){ u32 u=__float_as_uint(f); return (short)((u + 0x7fffu + ((u>>16)&1u))>>16); }
DEV float bf2f(short s){ return __uint_as_float(((u32)(unsigned short)s)<<16); }
DEV float sig_p(float x){ return 1.f/(1.f+expf(-x)); }
DEV float tanh_fast(float x){ float e=__expf(2.f*x); return 1.f-2.f/(e+1.f); }

// relaxed agent-scope (LLC-coherent, cache-bypassing) accessors
DEV u32  cohl4(const u32* p){ return __hip_atomic_load(p, __ATOMIC_RELAXED, __HIP_MEMORY_SCOPE_AGENT); }
DEV void cohs4(u32* p, u32 v){ __hip_atomic_store(p, v, __ATOMIC_RELAXED, __HIP_MEMORY_SCOPE_AGENT); }
DEV u64  cohl8(const void* p){ return __hip_atomic_load((const u64*)p, __ATOMIC_RELAXED, __HIP_MEMORY_SCOPE_AGENT); }
DEV void cohs8(void* p, u64 v){ __hip_atomic_store((u64*)p, v, __ATOMIC_RELAXED, __HIP_MEMORY_SCOPE_AGENT); }
DEV float cohlf(const float* p){ return __hip_atomic_load(p, __ATOMIC_RELAXED, __HIP_MEMORY_SCOPE_AGENT); }
DEV void cohsf(float* p, float v){ __hip_atomic_store(p, v, __ATOMIC_RELAXED, __HIP_MEMORY_SCOPE_AGENT); }
DEV void pollslot(const u32* s, u32 tgt){
  while (cohl4(s) < tgt) __builtin_amdgcn_s_sleep(1);
}

// ---------------- convert / transpose kernels ----------------

__global__ void cvt1d(const float* __restrict__ in, short* __restrict__ out, int n){
  int i = blockIdx.x*256 + threadIdx.x;
  if (i < n) out[i] = f2bf(in[i]);
}

// in f32 [R][C] -> out bf16 [Cpad][R]
__global__ void tconv(const float* __restrict__ in, short* __restrict__ out, int R, int C, int Cpad){
  __shared__ float t[32][33];
  int tx = threadIdx.x, ty = threadIdx.y;
  int c0 = blockIdx.x*32, r0 = blockIdx.y*32;
#pragma unroll
  for (int j=0;j<4;++j){
    int r = r0 + ty + 8*j, c = c0 + tx;
    t[ty+8*j][tx] = (c < C) ? in[(size_t)r*C + c] : 0.f;
  }
  __syncthreads();
#pragma unroll
  for (int j=0;j<4;++j){
    int oc = c0 + ty + 8*j;
    out[(size_t)oc*R + r0 + tx] = f2bf(t[tx][ty+8*j]);
  }
}

// batched transpose: in bf16 [NB][Dd][32] -> out bf16 [NB*32][Dd]
__global__ void btrans(const short* __restrict__ in, short* __restrict__ out, int Dd){
  __shared__ short t[32][33];
  int tx = threadIdx.x, ty = threadIdx.y;
  int d0 = blockIdx.x*32, s = blockIdx.y;
#pragma unroll
  for (int j=0;j<4;++j)
    t[ty+8*j][tx] = in[((size_t)s*Dd + d0 + ty + 8*j)*32 + tx];
  __syncthreads();
#pragma unroll
  for (int j=0;j<4;++j)
    out[((size_t)(s*32 + ty + 8*j))*Dd + d0 + tx] = t[tx][ty+8*j];
}

// [s][1536][32] -> [b][1536][128]  (per-col transpose of s/b planes)
__global__ void etrans(const short* __restrict__ in, short* __restrict__ out){
  __shared__ short t[128][33];
  int c = blockIdx.x, tid = threadIdx.x;
#pragma unroll
  for (int i=0;i<16;++i){
    int idx = tid + i*256;               // s = idx>>5, b = idx&31
    t[idx>>5][idx&31] = in[((size_t)(idx>>5)*1536 + c)*32 + (idx&31)];
  }
  __syncthreads();
#pragma unroll
  for (int i=0;i<16;++i){
    int idx = tid + i*256;               // b = idx>>7, s = idx&127
    out[((size_t)(idx>>7)*1536 + c)*128 + (idx&127)] = t[idx&127][idx>>7];
  }
}

__global__ void embed_k(const int* __restrict__ tok, const float* __restrict__ emb, short* __restrict__ X){
  int row = blockIdx.x;               // (s,b)
  int s = row >> 5, b = row & 31;
  int tv = tok[b*128 + s];
  X[(size_t)row*256 + threadIdx.x] = f2bf(emb[(size_t)tv*256 + threadIdx.x]);
}

// ---------------- MFMA GEMM  C = A[M,K] * BT[Npad][K] ----------------
template<int MODE>
__global__ __launch_bounds__(256) void gemm_k(
  const short* __restrict__ A, const short* __restrict__ BT,
  const float* __restrict__ bias, void* __restrict__ outp,
  float* __restrict__ psum, int Nreal, int K, int Ntot)
{
  const int m0 = blockIdx.y * 128, n0 = blockIdx.x * 128;
  const int tid = threadIdx.x, l = tid & 63, wv = tid >> 6;
  const int wm = wv >> 1, wn = wv & 1;
  __shared__ __align__(16) short As[128*64];
  __shared__ __align__(16) short Bs[128*64];
  f32x4 acc[4][4];
#pragma unroll
  for (int i=0;i<4;++i)
#pragma unroll
    for (int j=0;j<4;++j) acc[i][j] = (f32x4){0.f,0.f,0.f,0.f};

  const int nkb = K >> 6;
  for (int kb=0; kb<nkb; ++kb){
#pragma unroll
    for (int i=0;i<4;++i){
      int si = tid + i*256;
      int row = si >> 3, seg = si & 7;
      u32 off = (u32)(row*128 + seg*16) ^ (u32)((row&7)<<4);
      *(i32x4*)((char*)As + off) = *(const i32x4*)(A + (size_t)(m0+row)*K + kb*64 + seg*8);
      *(i32x4*)((char*)Bs + off) = *(const i32x4*)(BT + (size_t)(n0+row)*K + kb*64 + seg*8);
    }
    __syncthreads();
#pragma unroll
    for (int kt=0; kt<2; ++kt){
      bf16x8 af[4], bfv[4];
      int seg = kt*4 + (l>>4);
#pragma unroll
      for (int f=0; f<4; ++f){
        int ra = wm*64 + f*16 + (l&15);
        af[f]  = *(const bf16x8*)((char*)As + (((u32)(ra*128 + seg*16)) ^ ((u32)(ra&7)<<4)));
        int rb = wn*64 + f*16 + (l&15);
        bfv[f] = *(const bf16x8*)((char*)Bs + (((u32)(rb*128 + seg*16)) ^ ((u32)(rb&7)<<4)));
      }
#pragma unroll
      for (int mf=0; mf<4; ++mf)
#pragma unroll
        for (int nf=0; nf<4; ++nf)
          acc[mf][nf] = __builtin_amdgcn_mfma_f32_16x16x32_bf16(af[mf], bfv[nf], acc[mf][nf], 0,0,0);
    }
    __syncthreads();
  }

  if (MODE == 1){
    short* oT = (short*)outp;
#pragma unroll
    for (int mf=0; mf<4; ++mf){
      int r0 = m0 + wm*64 + mf*16 + ((l>>4)<<2);
      int s = r0 >> 5, b0 = r0 & 31;
#pragma unroll
      for (int nf=0; nf<4; ++nf){
        int col = n0 + wn*64 + nf*16 + (l&15);
        float bv = bias ? bias[col] : 0.f;
        short tmp[4];
#pragma unroll
        for (int j=0;j<4;++j) tmp[j] = f2bf(acc[mf][nf][j] + bv);
        *(i32x2*)(oT + ((size_t)s*Ntot + col)*32 + b0) = *(i32x2*)tmp;
      }
    }
  } else if (MODE == 3){
    short* o = (short*)outp;
#pragma unroll
    for (int mf=0; mf<4; ++mf){
      int r0 = m0 + wm*64 + mf*16 + ((l>>4)<<2);
#pragma unroll
      for (int nf=0; nf<4; ++nf){
        int col = n0 + wn*64 + nf*16 + (l&15);
        if (col < Nreal){
          float bv = bias ? bias[col] : 0.f;
#pragma unroll
          for (int j=0;j<4;++j) o[(size_t)(r0+j)*Nreal + col] = f2bf(acc[mf][nf][j] + bv);
        }
      }
    }
  } else { // MODE 2
    float* o = (float*)outp;
    int ncb = gridDim.x;
    float rs[4][4];
#pragma unroll
    for (int i=0;i<4;++i)
#pragma unroll
      for (int j=0;j<4;++j) rs[i][j]=0.f;
#pragma unroll
    for (int mf=0; mf<4; ++mf){
      int r0 = m0 + wm*64 + mf*16 + ((l>>4)<<2);
      int s = r0 >> 5, b0 = r0 & 31;
#pragma unroll
      for (int nf=0; nf<4; ++nf){
        int col = n0 + wn*64 + nf*16 + (l&15);
        if (col < Nreal){
          float bv = bias[col];
#pragma unroll
          for (int j=0;j<4;++j){
            float e = __expf(acc[mf][nf][j] + bv);
            o[(size_t)((b0+j)*128 + s)*Nreal + col] = e;
            rs[mf][j] += e;
          }
        }
      }
    }
#pragma unroll
    for (int mf=0; mf<4; ++mf)
#pragma unroll
      for (int j=0;j<4;++j){
        float v = rs[mf][j];
        v += __shfl_xor(v,1); v += __shfl_xor(v,2); v += __shfl_xor(v,4); v += __shfl_xor(v,8);
        if ((l&15)==0){
          int r = m0 + wm*64 + mf*16 + ((l>>4)<<2) + j;
          int orow = (r&31)*128 + (r>>5);
          psum[(size_t)orow*(2*ncb) + blockIdx.x*2 + wn] = v;
        }
      }
  }
}

// ---------------- encoder scan: 32 WGs (16/dir) x 512 thr ----------------
// WG owns 32 h-cols. Wh B-frags persistent in VGPR; h staged LDS per step.
// h state: hrowB u32 [dir][buf][32 b][256] packed bf16 pairs (coherent).
__global__ __launch_bounds__(512,1) void enc_scan(
  const short* __restrict__ gxfT, const short* __restrict__ gxbT,
  const short* __restrict__ WhfT, const short* __restrict__ WhbT,
  const float* __restrict__ brf, const float* __restrict__ brb,
  float* __restrict__ hT, u32* __restrict__ hrowB,
  short* __restrict__ encT, u32* __restrict__ flags)
{
  __shared__ __align__(16) short As[32*512];
  __shared__ float accL[96][36];
  __shared__ float brL[96];
  const int tid = threadIdx.x, wg = blockIdx.x;
  const int dir = wg >> 4, j = wg & 15;
  const short* gxT = dir ? gxbT : gxfT;
  const short* WT  = dir ? WhbT : WhfT;
  const float* br  = dir ? brb  : brf;
  float* hTd  = hT + (size_t)dir*2*16384;         // [2][512][32]
  u32* hrowBd = hrowB + (size_t)dir*2*8192;       // [2][32][256]
  u32* flg    = flags + dir*16*32;
  const int l = tid & 63, wv = tid >> 6;

  if (tid < 96) brL[tid] = br[(tid>>5)*512 + j*32 + (tid&31)];

  bf16x8 bfr[2][16];
  if (wv < 3){
#pragma unroll
    for (int p=0;p<2;++p){
      int gcol = wv*512 + j*32 + p*16 + (l&15);
      const short* bp = WT + (size_t)gcol*512 + ((l>>4)<<3);
#pragma unroll
      for (int kt=0; kt<16; ++kt) bfr[p][kt] = *(const bf16x8*)(bp + kt*32);
    }
  }

  for (int t=0; t<128; ++t){
    const int s = dir ? (127-t) : t;
    const int cur = t & 1, nxt = cur ^ 1;
    if (t > 0){
      if (tid < 16) pollslot(&flg[tid*32], (u32)t);
      __syncthreads();
    }
    // stage h (coherent) -> LDS swizzled
#pragma unroll
    for (int it=0; it<8; ++it){
      int u = tid + it*512;                 // 4096 8B units
      int b = u >> 7, k4 = u & 127;
      u64 v = cohl8(&hrowBd[(cur*32 + b)*256 + k4*2]);
      *(u64*)((char*)As + b*1024 + ((k4*8) ^ ((b&15)<<4))) = v;
    }
    __syncthreads();
    // gh = h @ Wh : waves 0..2, each 2 n-tiles, full K
    if (wv < 3){
      f32x4 acc[2][2];
#pragma unroll
      for (int m=0;m<2;++m){ acc[m][0]=(f32x4){0,0,0,0}; acc[m][1]=(f32x4){0,0,0,0}; }
#pragma unroll
      for (int kt=0; kt<16; ++kt){
#pragma unroll
        for (int m=0;m<2;++m){
          int row = m*16 + (l&15);
          int kbyte = (kt*4 + (l>>4))*16;
          bf16x8 af = *(const bf16x8*)((char*)As + row*1024 + (kbyte ^ ((row&15)<<4)));
          acc[m][0] = __builtin_amdgcn_mfma_f32_16x16x32_bf16(af, bfr[0][kt], acc[m][0], 0,0,0);
          acc[m][1] = __builtin_amdgcn_mfma_f32_16x16x32_bf16(af, bfr[1][kt], acc[m][1], 0,0,0);
        }
      }
#pragma unroll
      for (int m=0;m<2;++m)
#pragma unroll
        for (int p=0;p<2;++p)
          *(f32x4*)&accL[wv*32 + p*16 + (l&15)][m*16 + ((l>>4)<<2)] = acc[m][p];
    }
    __syncthreads();
    // pointwise: 32 hcols x 32 b, thread: b = tid&31, hcp = tid>>5 (2 hcols)
    {
      int b = tid & 31, hcp = tid >> 5;
      int hc0 = hcp*2;
      float hn[2];
#pragma unroll
      for (int q=0;q<2;++q){
        int hc = hc0 + q, hcol = j*32 + hc;
        float xz = bf2f(gxT[((size_t)s*1536 + hcol)*32 + b]);
        float xr = bf2f(gxT[((size_t)s*1536 + 512 + hcol)*32 + b]);
        float xh = bf2f(gxT[((size_t)s*1536 + 1024 + hcol)*32 + b]);
        float gz = accL[hc][b]    + brL[hc];
        float gr = accL[32+hc][b] + brL[32+hc];
        float gh = accL[64+hc][b] + brL[64+hc];
        float z = sig_p(xz + gz);
        float r = sig_p(xr + gr);
        float hcand = tanhf(xh + r*gh);
        float hp = hTd[cur*16384 + hcol*32 + b];
        hn[q] = z*hp + (1.f-z)*hcand;
        hTd[nxt*16384 + hcol*32 + b] = hn[q];
        encT[((size_t)s*1024 + dir*512 + hcol)*32 + b] = f2bf(hn[q]);
      }
      u32 pv = ((u32)(unsigned short)f2bf(hn[1])<<16) | (u32)(unsigned short)f2bf(hn[0]);
      cohs4(&hrowBd[(nxt*32 + b)*256 + j*16 + hcp], pv);
    }
    __syncthreads();
    if (tid == 0) cohs4(&flg[j*32], (u32)(t+1));
  }
}

// ---------------- decoder init ----------------
__global__ void dec_init(const float* __restrict__ src, float* __restrict__ hT_d,
                         float* __restrict__ hrowF, u32* __restrict__ hrowB){
  int i = blockIdx.x*256 + threadIdx.x;   // 8192 = 32 b x 256 k2
  int b = i >> 8, k2 = i & 255;
  float v0 = src[(k2*2)*32 + b];
  float v1 = src[(k2*2+1)*32 + b];
  hT_d[(k2*2)*32 + b] = v0;
  hT_d[(k2*2+1)*32 + b] = v1;
  hrowF[b*512 + k2*2] = v0;
  hrowF[b*512 + k2*2+1] = v1;
  hrowB[b*256 + k2] = ((u32)(unsigned short)f2bf(v1)<<16) | (u32)(unsigned short)f2bf(v0);
}

// ---------------- decoder scan: 48 WGs x 512 thr ----------------
// wg 0..15 : gates WG (32 h-cols, Wh B-frags in VGPR)
// wg 16..47: attention WG (one batch b) -> publishes ctxg[b][1536]
__global__ __launch_bounds__(512,1) void dec_scan(
  const short* __restrict__ gxeT, const short* __restrict__ encx,
  const short* __restrict__ WhdT, const float* __restrict__ brd,
  const short* __restrict__ Wa, const short* __restrict__ Uenc, const float* __restrict__ Va,
  float* __restrict__ hTd, float* __restrict__ hrowF, u32* __restrict__ hrowB,
  float* __restrict__ ctxg, short* __restrict__ decT,
  u32* __restrict__ hflag, u32* __restrict__ cflag)
{
  __shared__ __align__(16) short As[32*512];
  __shared__ float accL[96][36];
  __shared__ float brL[96];
  __shared__ float hs[512];
  __shared__ float whp[128*5];
  __shared__ float whv[128];
  __shared__ float scp[128*5];
  __shared__ float sc[128];
  __shared__ float red[4];
  __shared__ float vL[128];
  __shared__ float aL[128];

  const int tid = threadIdx.x, wg = blockIdx.x;
  const int l = tid & 63, wv = tid >> 6;

  if (wg < 16){
    // ---- gates WG j ----
    const int j = wg;
    if (tid < 96) brL[tid] = brd[(tid>>5)*512 + j*32 + (tid&31)];
    bf16x8 bfr[2][16];
    if (wv < 3){
#pragma unroll
      for (int p=0;p<2;++p){
        int gcol = wv*512 + j*32 + p*16 + (l&15);
        const short* bp = WhdT + (size_t)gcol*512 + ((l>>4)<<3);
#pragma unroll
        for (int kt=0; kt<16; ++kt) bfr[p][kt] = *(const bf16x8*)(bp + kt*32);
      }
    }
    for (int t=0; t<128; ++t){
      const int cur = t & 1, nxt = cur ^ 1;
      if (t > 0){
        if (tid < 16) pollslot(&hflag[tid*32], (u32)t);
        __syncthreads();
      }
      // stage h
#pragma unroll
      for (int it=0; it<8; ++it){
        int u = tid + it*512;
        int b = u >> 7, k4 = u & 127;
        u64 v = cohl8(&hrowB[((size_t)cur*32 + b)*256 + k4*2]);
        *(u64*)((char*)As + b*1024 + ((k4*8) ^ ((b&15)<<4))) = v;
      }
      __syncthreads();
      if (wv < 3){
        f32x4 acc[2][2];
#pragma unroll
        for (int m=0;m<2;++m){ acc[m][0]=(f32x4){0,0,0,0}; acc[m][1]=(f32x4){0,0,0,0}; }
#pragma unroll
        for (int kt=0; kt<16; ++kt){
#pragma unroll
          for (int m=0;m<2;++m){
            int row = m*16 + (l&15);
            int kbyte = (kt*4 + (l>>4))*16;
            bf16x8 af = *(const bf16x8*)((char*)As + row*1024 + (kbyte ^ ((row&15)<<4)));
            acc[m][0] = __builtin_amdgcn_mfma_f32_16x16x32_bf16(af, bfr[0][kt], acc[m][0], 0,0,0);
            acc[m][1] = __builtin_amdgcn_mfma_f32_16x16x32_bf16(af, bfr[1][kt], acc[m][1], 0,0,0);
          }
        }
#pragma unroll
        for (int m=0;m<2;++m)
#pragma unroll
          for (int p=0;p<2;++p)
            *(f32x4*)&accL[wv*32 + p*16 + (l&15)][m*16 + ((l>>4)<<2)] = acc[m][p];
      } else if (tid >= 448 && tid < 480){
        pollslot(&cflag[(tid-448)*32], (u32)(t+1));   // wave 7 polls ctx flags
      }
      __syncthreads();
      // pointwise
      {
        int b = tid & 31, hcp = tid >> 5;
        int hc0 = hcp*2;
        float hn[2];
#pragma unroll
        for (int q=0;q<2;++q){
          int hc = hc0 + q, hcol = j*32 + hc;
          float xz = bf2f(gxeT[((size_t)t*1536 + hcol)*32 + b])        + cohlf(&ctxg[b*1536 + hcol]);
          float xr = bf2f(gxeT[((size_t)t*1536 + 512 + hcol)*32 + b])  + cohlf(&ctxg[b*1536 + 512 + hcol]);
          float xh = bf2f(gxeT[((size_t)t*1536 + 1024 + hcol)*32 + b]) + cohlf(&ctxg[b*1536 + 1024 + hcol]);
          float gz = accL[hc][b]    + brL[hc];
          float gr = accL[32+hc][b] + brL[32+hc];
          float gh = accL[64+hc][b] + brL[64+hc];
          float z = sig_p(xz + gz);
          float r = sig_p(xr + gr);
          float hcand = tanhf(xh + r*gh);
          float hp = hTd[cur*16384 + hcol*32 + b];
          hn[q] = z*hp + (1.f-z)*hcand;
          hTd[nxt*16384 + hcol*32 + b] = hn[q];
          decT[((size_t)t*512 + hcol)*32 + b] = f2bf(hn[q]);
        }
        u32 pv = ((u32)(unsigned short)f2bf(hn[1])<<16) | (u32)(unsigned short)f2bf(hn[0]);
        cohs4(&hrowB[((size_t)nxt*32 + b)*256 + j*16 + hcp], pv);
        u64 fv = ((u64)__float_as_uint(hn[1])<<32) | (u64)__float_as_uint(hn[0]);
        cohs8(&hrowF[((size_t)nxt*32 + b)*512 + j*32 + hc0], fv);
      }
      __syncthreads();
      if (tid == 0) cohs4(&hflag[j*32], (u32)(t+1));
    }
  } else {
    // ---- attention WG, batch b ----
    const int b = wg - 16;
    u32 wa[64];
    {
      const u32* wp = (const u32*)(Wa + (size_t)(tid&127)*512 + (tid>>7)*128);
#pragma unroll
      for (int i=0;i<64;++i) wa[i] = wp[i];
    }
    u32 ue[16];
    {
      int s = tid & 127, aq = tid >> 7;
      const u32* up = (const u32*)(Uenc + ((size_t)(s*32 + b))*128 + aq*32);
#pragma unroll
      for (int i=0;i<16;++i) ue[i] = up[i];
    }
    if (tid < 128) vL[tid] = Va[tid];
    const short* eb = encx + (size_t)b*1536*128;

    for (int t=0; t<128; ++t){
      const int cur = t & 1;
      if (t > 0){
        if (tid < 16) pollslot(&hflag[tid*32], (u32)t);
      }
      __syncthreads();
      hs[tid] = cohlf(&hrowF[((size_t)cur*32 + b)*512 + tid]);
      __syncthreads();
      // wh = h @ Wa^T (k split 4-way)
      {
        int a = tid & 127, kq2 = tid >> 7;
        float p = 0.f;
        const float* hp2 = &hs[kq2*128];
#pragma unroll 8
        for (int i=0;i<64;++i){
          u32 w2 = wa[i];
          float2 h2 = *(const float2*)(hp2 + 2*i);
          p += bf2f((short)(w2 & 0xffff))*h2.x + bf2f((short)(w2 >> 16))*h2.y;
        }
        whp[a*5 + kq2] = p;
      }
      __syncthreads();
      if (tid < 128) whv[tid] = whp[tid*5]+whp[tid*5+1]+whp[tid*5+2]+whp[tid*5+3];
      __syncthreads();
      // score_s = sum_a tanh(wh_a + Uenc) * v_a (a split 4-way)
      {
        int s = tid & 127, aq = tid >> 7;
        float p = 0.f;
#pragma unroll 4
        for (int i=0;i<16;++i){
          u32 u2 = ue[i];
          int a0 = aq*32 + 2*i;
          p += tanh_fast(whv[a0]   + bf2f((short)(u2 & 0xffff))) * vL[a0];
          p += tanh_fast(whv[a0+1] + bf2f((short)(u2 >> 16)))    * vL[a0+1];
        }
        scp[s*5 + aq] = p;
      }
      __syncthreads();
      if (tid < 128) sc[tid] = scp[tid*5]+scp[tid*5+1]+scp[tid*5+2]+scp[tid*5+3];
      __syncthreads();
      float ev = 0.f;
      if (tid < 128){
        float v = sc[tid], mx = v;
#pragma unroll
        for (int d2=32; d2; d2>>=1) mx = fmaxf(mx, __shfl_xor(mx, d2));
        if ((tid & 63) == 0) red[tid>>6] = mx;
      }
      __syncthreads();
      if (tid < 128){
        float mx = fmaxf(red[0], red[1]);
        ev = __expf(sc[tid] - mx);
        float sm = ev;
#pragma unroll
        for (int d2=32; d2; d2>>=1) sm += __shfl_xor(sm, d2);
        if ((tid & 63) == 0) red[2 + (tid>>6)] = sm;
      }
      __syncthreads();
      if (tid < 128) aL[tid] = ev / (red[2] + red[3]);
      __syncthreads();
      // ctxgate: 3 cols per thread: ctxg[b][col] = sum_s alpha_s * ENCX[b][col][s]
      {
        int col = tid*3;
        float a0=0.f, a1=0.f, a2=0.f;
        const short* e0 = eb + (size_t)col*128;
#pragma unroll
        for (int sb=0; sb<16; ++sb){
          f32x4 av0 = *(const f32x4*)&aL[sb*8];
          f32x4 av1 = *(const f32x4*)&aL[sb*8+4];
          bf16x8 ev0 = *(const bf16x8*)(e0 + sb*8);
          bf16x8 ev1 = *(const bf16x8*)(e0 + 128 + sb*8);
          bf16x8 ev2 = *(const bf16x8*)(e0 + 256 + sb*8);
#pragma unroll
          for (int i=0;i<4;++i){
            a0 += bf2f(ev0[i])*av0[i]; a1 += bf2f(ev1[i])*av0[i]; a2 += bf2f(ev2[i])*av0[i];
            a0 += bf2f(ev0[4+i])*av1[i]; a1 += bf2f(ev1[4+i])*av1[i]; a2 += bf2f(ev2[4+i])*av1[i];
          }
        }
        cohsf(&ctxg[b*1536 + col], a0);
        cohsf(&ctxg[b*1536 + col+1], a1);
        cohsf(&ctxg[b*1536 + col+2], a2);
      }
      __syncthreads();
      if (tid == 0) cohs4(&cflag[b*32], (u32)(t+1));
    }
  }
}

// ---------------- softmax finish ----------------
__global__ void scale_rows(float* __restrict__ out, const float* __restrict__ psum,
                           int ncols, int w){
  int r = blockIdx.x;
  __shared__ float ssum[256];
  float s = 0.f;
  for (int i = threadIdx.x; i < w; i += 256) s += psum[(size_t)r*w + i];
  ssum[threadIdx.x] = s; __syncthreads();
  for (int d = 128; d; d >>= 1){
    if (threadIdx.x < d) ssum[threadIdx.x] += ssum[threadIdx.x + d];
    __syncthreads();
  }
  float v = 1.f/ssum[0];
  float* p = out + (size_t)r*ncols;
  for (int i = threadIdx.x; i < ncols; i += 256) p[i] *= v;
}

// ---------------- host ----------------
extern "C" void kernel_launch(void* const* d_in, const int* in_sizes, int n_in,
                              void* d_out, int out_size, void* d_ws, size_t ws_size,
                              hipStream_t stream)
{
  const int*   tokens=(const int*)  d_in[0];
  const float* emb  =(const float*)d_in[1];
  const float* Wx_f =(const float*)d_in[2];
  const float* Wh_f =(const float*)d_in[3];
  const float* bi_f =(const float*)d_in[4];
  const float* br_f =(const float*)d_in[5];
  const float* Wx_b =(const float*)d_in[6];
  const float* Wh_b =(const float*)d_in[7];
  const float* bi_b =(const float*)d_in[8];
  const float* br_b =(const float*)d_in[9];
  const float* W_a  =(const float*)d_in[10];
  const float* U_a  =(const float*)d_in[11];
  const float* V_a  =(const float*)d_in[12];
  const float* Wx_d =(const float*)d_in[13];
  const float* Wh_d =(const float*)d_in[14];
  const float* bi_d =(const float*)d_in[15];
  const float* br_d =(const float*)d_in[16];
  const float* Wo   =(const float*)d_in[17];
  const float* bo   =(const float*)d_in[18];

  const int NV = 32001, NVP = 32128, NCB = 251;

  char* base = (char*)d_ws; size_t off = 0;
  auto alloc = [&](size_t bytes)->char*{
    off = (off + 255) & ~(size_t)255;
    char* p = base + off; off += bytes; return p;
  };
  u32*   flags  = (u32*)  alloc(16384);  // eflag [0..1023], hflag [1024..2047], cflag [2048..]
  short* X      = (short*)alloc((size_t)4096*256*2);
  short* WxfT   = (short*)alloc((size_t)1536*256*2);
  short* WxbT   = (short*)alloc((size_t)1536*256*2);
  short* WhfT   = (short*)alloc((size_t)1536*512*2);
  short* WhbT   = (short*)alloc((size_t)1536*512*2);
  short* WhdT   = (short*)alloc((size_t)1536*512*2);
  short* WxeT   = (short*)alloc((size_t)1536*1024*2);
  short* WxcT   = (short*)alloc((size_t)1536*1024*2);
  short* WoT    = (short*)alloc((size_t)NVP*512*2);
  short* UaB    = (short*)alloc((size_t)128*1024*2);
  short* WaB    = (short*)alloc((size_t)128*512*2);
  short* gxfT   = (short*)alloc((size_t)128*1536*32*2);
  short* gxbT   = (short*)alloc((size_t)128*1536*32*2);
  short* encT   = (short*)alloc((size_t)128*1024*32*2);
  short* encRow = (short*)alloc((size_t)4096*1024*2);
  short* Uenc   = (short*)alloc((size_t)4096*128*2);
  short* gxeT   = (short*)alloc((size_t)128*1536*32*2);
  short* encxT1 = (short*)alloc((size_t)128*1536*32*2);   // [s][1536][32]
  short* encx   = (short*)alloc((size_t)32*1536*128*2);   // [b][1536][128]
  short* decT   = (short*)alloc((size_t)128*512*32*2);
  short* decRow = (short*)alloc((size_t)4096*512*2);
  float* hT_e   = (float*)alloc((size_t)2*2*512*32*4);
  u32*   hrowB_e= (u32*)  alloc((size_t)2*2*32*256*4);
  float* hT_d   = (float*)alloc((size_t)2*512*32*4);
  float* hrowF_d= (float*)alloc((size_t)2*32*512*4);
  u32*   hrowB_d= (u32*)  alloc((size_t)2*32*256*4);
  float* ctxg   = (float*)alloc((size_t)32*1536*4);
  float* psum   = (float*)alloc((size_t)4096*2*NCB*4);

  hipMemsetAsync(flags, 0, 16384, stream);
  hipMemsetAsync(hT_e, 0, (size_t)2*2*512*32*4, stream);
  hipMemsetAsync(hrowB_e, 0, (size_t)2*2*32*256*4, stream);

  // weight conversions (all BT = [N][K] bf16)
  tconv<<<dim3(1536/32,256/32),dim3(32,8),0,stream>>>(Wx_f, WxfT, 256, 1536, 1536);
  tconv<<<dim3(1536/32,256/32),dim3(32,8),0,stream>>>(Wx_b, WxbT, 256, 1536, 1536);
  tconv<<<dim3(1536/32,512/32),dim3(32,8),0,stream>>>(Wh_f, WhfT, 512, 1536, 1536);
  tconv<<<dim3(1536/32,512/32),dim3(32,8),0,stream>>>(Wh_b, WhbT, 512, 1536, 1536);
  tconv<<<dim3(1536/32,512/32),dim3(32,8),0,stream>>>(Wh_d, WhdT, 512, 1536, 1536);
  tconv<<<dim3(1536/32,1024/32),dim3(32,8),0,stream>>>(Wx_d,                    WxeT, 1024, 1536, 1536);
  tconv<<<dim3(1536/32,1024/32),dim3(32,8),0,stream>>>(Wx_d+(size_t)1024*1536,  WxcT, 1024, 1536, 1536);
  tconv<<<dim3(NVP/32,512/32),dim3(32,8),0,stream>>>(Wo, WoT, 512, NV, NVP);
  cvt1d<<<(128*512+255)/256,256,0,stream>>>(W_a, WaB, 128*512);
  cvt1d<<<(128*1024+255)/256,256,0,stream>>>(U_a, UaB, 128*1024);

  embed_k<<<4096,256,0,stream>>>(tokens, emb, X);

  gemm_k<1><<<dim3(12,32),256,0,stream>>>(X, WxfT, bi_f, gxfT, nullptr, 1536, 256, 1536);
  gemm_k<1><<<dim3(12,32),256,0,stream>>>(X, WxbT, bi_b, gxbT, nullptr, 1536, 256, 1536);

  enc_scan<<<32,512,0,stream>>>(gxfT, gxbT, WhfT, WhbT, br_f, br_b,
                                hT_e, hrowB_e, encT, flags);

  btrans<<<dim3(1024/32,128),dim3(32,8),0,stream>>>(encT, encRow, 1024);

  gemm_k<3><<<dim3(1,32),256,0,stream>>>(encRow, UaB, nullptr, Uenc, nullptr, 128, 1024, 128);
  gemm_k<1><<<dim3(12,32),256,0,stream>>>(encRow, WxeT, bi_d, gxeT, nullptr, 1536, 1024, 1536);
  gemm_k<1><<<dim3(12,32),256,0,stream>>>(encRow, WxcT, nullptr, encxT1, nullptr, 1536, 1024, 1536);
  etrans<<<1536,256,0,stream>>>(encxT1, encx);

  // decoder h0 = backward final h (dir=1, buf0)
  dec_init<<<32,256,0,stream>>>(hT_e + 32768, hT_d, hrowF_d, hrowB_d);

  dec_scan<<<48,512,0,stream>>>(gxeT, encx, WhdT, br_d, WaB, Uenc, V_a,
                                hT_d, hrowF_d, hrowB_d, ctxg, decT,
                                &flags[1024], &flags[2048]);

  btrans<<<dim3(512/32,128),dim3(32,8),0,stream>>>(decT, decRow, 512);

  gemm_k<2><<<dim3(NCB,32),256,0,stream>>>(decRow, WoT, bo, d_out, psum, NV, 512, NV);

  scale_rows<<<4096,256,0,stream>>>((float*)d_out, psum, NV, 2*NCB);
}

// Round 4
// 4027.833 us; speedup vs baseline: 1.7108x; 1.2899x over previous
//
#include <hip/hip_runtime.h>
#include <stdint.h>

typedef unsigned int u32;
typedef unsigned long long u64;
typedef __attribute__((ext_vector_type(8))) short bf16x8;
typedef __attribute__((ext_vector_type(4))) float f32x4;
typedef __attribute__((ext_vector_type(4))) int i32x4;
typedef __attribute__((ext_vector_type(2))) int i32x2;

#define DEV static __device__ __forceinline__

DEV short f2bf(float f){ u32 u=__float_as_uint(f); return (short)((u + 0x7fffu + ((u>>16)&1u))>>16); }
DEV float bf2f(short s){ return __uint_as_float(((u32)(unsigned short)s)<<16); }
DEV float sig_p(float x){ return 1.f/(1.f+expf(-x)); }
DEV float tanh_fast(float x){ float e=__expf(2.f*x); return 1.f-2.f/(e+1.f); }

// relaxed agent-scope (LLC-coherent) accessors
DEV u32  cohl4(const u32* p){ return __hip_atomic_load(p, __ATOMIC_RELAXED, __HIP_MEMORY_SCOPE_AGENT); }
DEV void cohs4(u32* p, u32 v){ __hip_atomic_store(p, v, __ATOMIC_RELAXED, __HIP_MEMORY_SCOPE_AGENT); }
DEV u64  cohl8(const void* p){ return __hip_atomic_load((const u64*)p, __ATOMIC_RELAXED, __HIP_MEMORY_SCOPE_AGENT); }
DEV float cohlf(const float* p){ return __hip_atomic_load(p, __ATOMIC_RELAXED, __HIP_MEMORY_SCOPE_AGENT); }
DEV void cohsf(float* p, float v){ __hip_atomic_store(p, v, __ATOMIC_RELAXED, __HIP_MEMORY_SCOPE_AGENT); }
DEV void pollslot(const u32* s, u32 tgt){
  while (cohl4(s) < tgt) __builtin_amdgcn_s_sleep(1);
}

// ---------------- convert / transpose kernels ----------------

__global__ void cvt1d(const float* __restrict__ in, short* __restrict__ out, int n){
  int i = blockIdx.x*256 + threadIdx.x;
  if (i < n) out[i] = f2bf(in[i]);
}

// in f32 [R][C] -> out bf16 [Cpad][R]
__global__ void tconv(const float* __restrict__ in, short* __restrict__ out, int R, int C, int Cpad){
  __shared__ float t[32][33];
  int tx = threadIdx.x, ty = threadIdx.y;
  int c0 = blockIdx.x*32, r0 = blockIdx.y*32;
#pragma unroll
  for (int j=0;j<4;++j){
    int r = r0 + ty + 8*j, c = c0 + tx;
    t[ty+8*j][tx] = (c < C) ? in[(size_t)r*C + c] : 0.f;
  }
  __syncthreads();
#pragma unroll
  for (int j=0;j<4;++j){
    int oc = c0 + ty + 8*j;
    out[(size_t)oc*R + r0 + tx] = f2bf(t[tx][ty+8*j]);
  }
}

// batched transpose: in bf16 [NB][Dd][32] -> out bf16 [NB*32][Dd]
__global__ void btrans(const short* __restrict__ in, short* __restrict__ out, int Dd){
  __shared__ short t[32][33];
  int tx = threadIdx.x, ty = threadIdx.y;
  int d0 = blockIdx.x*32, s = blockIdx.y;
#pragma unroll
  for (int j=0;j<4;++j)
    t[ty+8*j][tx] = in[((size_t)s*Dd + d0 + ty + 8*j)*32 + tx];
  __syncthreads();
#pragma unroll
  for (int j=0;j<4;++j)
    out[((size_t)(s*32 + ty + 8*j))*Dd + d0 + tx] = t[tx][ty+8*j];
}

// [s][1536][32] -> [b][1536][128]
__global__ void etrans(const short* __restrict__ in, short* __restrict__ out){
  __shared__ short t[128][33];
  int c = blockIdx.x, tid = threadIdx.x;
#pragma unroll
  for (int i=0;i<16;++i){
    int idx = tid + i*256;
    t[idx>>5][idx&31] = in[((size_t)(idx>>5)*1536 + c)*32 + (idx&31)];
  }
  __syncthreads();
#pragma unroll
  for (int i=0;i<16;++i){
    int idx = tid + i*256;
    out[((size_t)(idx>>7)*1536 + c)*128 + (idx&127)] = t[idx&127][idx>>7];
  }
}

__global__ void embed_k(const int* __restrict__ tok, const float* __restrict__ emb, short* __restrict__ X){
  int row = blockIdx.x;               // (s,b)
  int s = row >> 5, b = row & 31;
  int tv = tok[b*128 + s];
  X[(size_t)row*256 + threadIdx.x] = f2bf(emb[(size_t)tv*256 + threadIdx.x]);
}

// ---------------- MFMA GEMM  C = A[M,K] * BT[Npad][K] ----------------
template<int MODE>
__global__ __launch_bounds__(256) void gemm_k(
  const short* __restrict__ A, const short* __restrict__ BT,
  const float* __restrict__ bias, void* __restrict__ outp,
  float* __restrict__ psum, int Nreal, int K, int Ntot)
{
  const int m0 = blockIdx.y * 128, n0 = blockIdx.x * 128;
  const int tid = threadIdx.x, l = tid & 63, wv = tid >> 6;
  const int wm = wv >> 1, wn = wv & 1;
  __shared__ __align__(16) short As[128*64];
  __shared__ __align__(16) short Bs[128*64];
  f32x4 acc[4][4];
#pragma unroll
  for (int i=0;i<4;++i)
#pragma unroll
    for (int j=0;j<4;++j) acc[i][j] = (f32x4){0.f,0.f,0.f,0.f};

  const int nkb = K >> 6;
  for (int kb=0; kb<nkb; ++kb){
#pragma unroll
    for (int i=0;i<4;++i){
      int si = tid + i*256;
      int row = si >> 3, seg = si & 7;
      u32 off = (u32)(row*128 + seg*16) ^ (u32)((row&7)<<4);
      *(i32x4*)((char*)As + off) = *(const i32x4*)(A + (size_t)(m0+row)*K + kb*64 + seg*8);
      *(i32x4*)((char*)Bs + off) = *(const i32x4*)(BT + (size_t)(n0+row)*K + kb*64 + seg*8);
    }
    __syncthreads();
#pragma unroll
    for (int kt=0; kt<2; ++kt){
      bf16x8 af[4], bfv[4];
      int seg = kt*4 + (l>>4);
#pragma unroll
      for (int f=0; f<4; ++f){
        int ra = wm*64 + f*16 + (l&15);
        af[f]  = *(const bf16x8*)((char*)As + (((u32)(ra*128 + seg*16)) ^ ((u32)(ra&7)<<4)));
        int rb = wn*64 + f*16 + (l&15);
        bfv[f] = *(const bf16x8*)((char*)Bs + (((u32)(rb*128 + seg*16)) ^ ((u32)(rb&7)<<4)));
      }
#pragma unroll
      for (int mf=0; mf<4; ++mf)
#pragma unroll
        for (int nf=0; nf<4; ++nf)
          acc[mf][nf] = __builtin_amdgcn_mfma_f32_16x16x32_bf16(af[mf], bfv[nf], acc[mf][nf], 0,0,0);
    }
    __syncthreads();
  }

  if (MODE == 1){
    short* oT = (short*)outp;
#pragma unroll
    for (int mf=0; mf<4; ++mf){
      int r0 = m0 + wm*64 + mf*16 + ((l>>4)<<2);
      int s = r0 >> 5, b0 = r0 & 31;
#pragma unroll
      for (int nf=0; nf<4; ++nf){
        int col = n0 + wn*64 + nf*16 + (l&15);
        float bv = bias ? bias[col] : 0.f;
        short tmp[4];
#pragma unroll
        for (int j=0;j<4;++j) tmp[j] = f2bf(acc[mf][nf][j] + bv);
        *(i32x2*)(oT + ((size_t)s*Ntot + col)*32 + b0) = *(i32x2*)tmp;
      }
    }
  } else if (MODE == 3){
    short* o = (short*)outp;
#pragma unroll
    for (int mf=0; mf<4; ++mf){
      int r0 = m0 + wm*64 + mf*16 + ((l>>4)<<2);
#pragma unroll
      for (int nf=0; nf<4; ++nf){
        int col = n0 + wn*64 + nf*16 + (l&15);
        if (col < Nreal){
          float bv = bias ? bias[col] : 0.f;
#pragma unroll
          for (int j=0;j<4;++j) o[(size_t)(r0+j)*Nreal + col] = f2bf(acc[mf][nf][j] + bv);
        }
      }
    }
  } else { // MODE 2
    float* o = (float*)outp;
    int ncb = gridDim.x;
    float rs[4][4];
#pragma unroll
    for (int i=0;i<4;++i)
#pragma unroll
      for (int j=0;j<4;++j) rs[i][j]=0.f;
#pragma unroll
    for (int mf=0; mf<4; ++mf){
      int r0 = m0 + wm*64 + mf*16 + ((l>>4)<<2);
      int s = r0 >> 5, b0 = r0 & 31;
#pragma unroll
      for (int nf=0; nf<4; ++nf){
        int col = n0 + wn*64 + nf*16 + (l&15);
        if (col < Nreal){
          float bv = bias[col];
#pragma unroll
          for (int j=0;j<4;++j){
            float e = __expf(acc[mf][nf][j] + bv);
            o[(size_t)((b0+j)*128 + s)*Nreal + col] = e;
            rs[mf][j] += e;
          }
        }
      }
    }
#pragma unroll
    for (int mf=0; mf<4; ++mf)
#pragma unroll
      for (int j=0;j<4;++j){
        float v = rs[mf][j];
        v += __shfl_xor(v,1); v += __shfl_xor(v,2); v += __shfl_xor(v,4); v += __shfl_xor(v,8);
        if ((l&15)==0){
          int r = m0 + wm*64 + mf*16 + ((l>>4)<<2) + j;
          int orow = (r&31)*128 + (r>>5);
          psum[(size_t)orow*(2*ncb) + blockIdx.x*2 + wn] = v;
        }
      }
  }
}

// ---------------- encoder scan: 32 WGs (16/dir) x 512 thr (unchanged) ----------------
__global__ __launch_bounds__(512,1) void enc_scan(
  const short* __restrict__ gxfT, const short* __restrict__ gxbT,
  const short* __restrict__ WhfT, const short* __restrict__ WhbT,
  const float* __restrict__ brf, const float* __restrict__ brb,
  float* __restrict__ hT, u32* __restrict__ hrowB,
  short* __restrict__ encT, u32* __restrict__ flags)
{
  __shared__ __align__(16) short As[32*512];
  __shared__ float accL[96][36];
  __shared__ float brL[96];
  const int tid = threadIdx.x, wg = blockIdx.x;
  const int dir = wg >> 4, j = wg & 15;
  const short* gxT = dir ? gxbT : gxfT;
  const short* WT  = dir ? WhbT : WhfT;
  const float* br  = dir ? brb  : brf;
  float* hTd  = hT + (size_t)dir*2*16384;
  u32* hrowBd = hrowB + (size_t)dir*2*8192;
  u32* flg    = flags + dir*16*32;
  const int l = tid & 63, wv = tid >> 6;

  if (tid < 96) brL[tid] = br[(tid>>5)*512 + j*32 + (tid&31)];

  bf16x8 bfr[2][16];
  if (wv < 3){
#pragma unroll
    for (int p=0;p<2;++p){
      int gcol = wv*512 + j*32 + p*16 + (l&15);
      const short* bp = WT + (size_t)gcol*512 + ((l>>4)<<3);
#pragma unroll
      for (int kt=0; kt<16; ++kt) bfr[p][kt] = *(const bf16x8*)(bp + kt*32);
    }
  }

  for (int t=0; t<128; ++t){
    const int s = dir ? (127-t) : t;
    const int cur = t & 1, nxt = cur ^ 1;
    if (t > 0){
      if (tid < 16) pollslot(&flg[tid*32], (u32)t);
      __syncthreads();
    }
#pragma unroll
    for (int it=0; it<8; ++it){
      int u = tid + it*512;
      int b = u >> 7, k4 = u & 127;
      u64 v = cohl8(&hrowBd[(cur*32 + b)*256 + k4*2]);
      *(u64*)((char*)As + b*1024 + ((k4*8) ^ ((b&15)<<4))) = v;
    }
    __syncthreads();
    if (wv < 3){
      f32x4 acc[2][2];
#pragma unroll
      for (int m=0;m<2;++m){ acc[m][0]=(f32x4){0,0,0,0}; acc[m][1]=(f32x4){0,0,0,0}; }
#pragma unroll
      for (int kt=0; kt<16; ++kt){
#pragma unroll
        for (int m=0;m<2;++m){
          int row = m*16 + (l&15);
          int kbyte = (kt*4 + (l>>4))*16;
          bf16x8 af = *(const bf16x8*)((char*)As + row*1024 + (kbyte ^ ((row&15)<<4)));
          acc[m][0] = __builtin_amdgcn_mfma_f32_16x16x32_bf16(af, bfr[0][kt], acc[m][0], 0,0,0);
          acc[m][1] = __builtin_amdgcn_mfma_f32_16x16x32_bf16(af, bfr[1][kt], acc[m][1], 0,0,0);
        }
      }
#pragma unroll
      for (int m=0;m<2;++m)
#pragma unroll
        for (int p=0;p<2;++p)
          *(f32x4*)&accL[wv*32 + p*16 + (l&15)][m*16 + ((l>>4)<<2)] = acc[m][p];
    }
    __syncthreads();
    {
      int b = tid & 31, hcp = tid >> 5;
      int hc0 = hcp*2;
      float hn[2];
#pragma unroll
      for (int q=0;q<2;++q){
        int hc = hc0 + q, hcol = j*32 + hc;
        float xz = bf2f(gxT[((size_t)s*1536 + hcol)*32 + b]);
        float xr = bf2f(gxT[((size_t)s*1536 + 512 + hcol)*32 + b]);
        float xh = bf2f(gxT[((size_t)s*1536 + 1024 + hcol)*32 + b]);
        float gz = accL[hc][b]    + brL[hc];
        float gr = accL[32+hc][b] + brL[32+hc];
        float gh = accL[64+hc][b] + brL[64+hc];
        float z = sig_p(xz + gz);
        float r = sig_p(xr + gr);
        float hcand = tanhf(xh + r*gh);
        float hp = hTd[cur*16384 + hcol*32 + b];
        hn[q] = z*hp + (1.f-z)*hcand;
        hTd[nxt*16384 + hcol*32 + b] = hn[q];
        encT[((size_t)s*1024 + dir*512 + hcol)*32 + b] = f2bf(hn[q]);
      }
      u32 pv = ((u32)(unsigned short)f2bf(hn[1])<<16) | (u32)(unsigned short)f2bf(hn[0]);
      cohs4(&hrowBd[(nxt*32 + b)*256 + j*16 + hcp], pv);
    }
    __syncthreads();
    if (tid == 0) cohs4(&flg[j*32], (u32)(t+1));
  }
}

// ---------------- decoder init: fill hrowB buf0 ----------------
__global__ void dec_init(const float* __restrict__ src, u32* __restrict__ hrowB){
  int i = blockIdx.x*256 + threadIdx.x;   // 8192 = 32 b x 256 k2
  int b = i >> 8, k2 = i & 255;
  float v0 = src[(k2*2)*32 + b];
  float v1 = src[(k2*2+1)*32 + b];
  hrowB[b*256 + k2] = ((u32)(unsigned short)f2bf(v1)<<16) | (u32)(unsigned short)f2bf(v0);
}

// ---------------- decoder scan: 48 WGs x 512 thr ----------------
// wg 0..15 : gh WG j (32 hcols, Whd frags in VGPR): h -> GH[j][b][96]
// wg 16..47: attn+GRU WG, one batch b: full attention + pointwise, owns h[b]
__global__ __launch_bounds__(512,1) void dec_scan(
  const short* __restrict__ gxeR,   // [(t*32+b)][1536] bf16 (incl bi_d)
  const short* __restrict__ encx,   // [b][1536][128] bf16
  const short* __restrict__ WhdT,   // [1536][512] bf16
  const float* __restrict__ brd,
  const short* __restrict__ Wa, const short* __restrict__ Uenc, const float* __restrict__ Va,
  const float* __restrict__ h0,     // [512][32] f32
  u32* __restrict__ hrowB,          // [2][32][256] u32 (bf16 pairs)
  float* __restrict__ GH,           // [16*32][96] f32
  short* __restrict__ decRow,       // [(t*32+b)][512] bf16
  u32* __restrict__ hflag, u32* __restrict__ gflag)
{
  // gh-WG shared
  __shared__ __align__(16) short As[32*512];
  __shared__ float accL[96][36];
  // attn-WG shared
  __shared__ float hs[512];
  __shared__ short hb[512];
  __shared__ float gxc[1536];
  __shared__ float brA[1536];
  __shared__ float whp[128*5];
  __shared__ float whv[128];
  __shared__ float scp[128*5];
  __shared__ float sc[128];
  __shared__ float red[4];
  __shared__ float vL[128];
  __shared__ float aL[128];

  const int tid = threadIdx.x, wg = blockIdx.x;
  const int l = tid & 63, wv = tid >> 6;

  if (wg < 16){
    // ---- gh WG j ----
    const int j = wg;
    bf16x8 bfr[2][16];
    if (wv < 3){
#pragma unroll
      for (int p=0;p<2;++p){
        int gcol = wv*512 + j*32 + p*16 + (l&15);
        const short* bp = WhdT + (size_t)gcol*512 + ((l>>4)<<3);
#pragma unroll
        for (int kt=0; kt<16; ++kt) bfr[p][kt] = *(const bf16x8*)(bp + kt*32);
      }
    }
    for (int t=0; t<128; ++t){
      const int cur = t & 1;
      if (t > 0){
        if (tid < 32) pollslot(&hflag[tid*32], (u32)t);
        __syncthreads();
      }
      // stage h^{(t)}
#pragma unroll
      for (int it=0; it<8; ++it){
        int u = tid + it*512;
        int b = u >> 7, k4 = u & 127;
        u64 v = cohl8(&hrowB[((size_t)cur*32 + b)*256 + k4*2]);
        *(u64*)((char*)As + b*1024 + ((k4*8) ^ ((b&15)<<4))) = v;
      }
      __syncthreads();
      if (wv < 3){
        f32x4 acc[2][2];
#pragma unroll
        for (int m=0;m<2;++m){ acc[m][0]=(f32x4){0,0,0,0}; acc[m][1]=(f32x4){0,0,0,0}; }
#pragma unroll
        for (int kt=0; kt<16; ++kt){
#pragma unroll
          for (int m=0;m<2;++m){
            int row = m*16 + (l&15);
            int kbyte = (kt*4 + (l>>4))*16;
            bf16x8 af = *(const bf16x8*)((char*)As + row*1024 + (kbyte ^ ((row&15)<<4)));
            acc[m][0] = __builtin_amdgcn_mfma_f32_16x16x32_bf16(af, bfr[0][kt], acc[m][0], 0,0,0);
            acc[m][1] = __builtin_amdgcn_mfma_f32_16x16x32_bf16(af, bfr[1][kt], acc[m][1], 0,0,0);
          }
        }
#pragma unroll
        for (int m=0;m<2;++m)
#pragma unroll
          for (int p=0;p<2;++p)
            *(f32x4*)&accL[wv*32 + p*16 + (l&15)][m*16 + ((l>>4)<<2)] = acc[m][p];
      }
      __syncthreads();
      // publish GH (coalesced full-line stores)
#pragma unroll
      for (int p=0;p<6;++p){
        int idx = p*512 + tid;
        int b = idx / 96;
        int cp = idx - b*96;
        cohsf(&GH[((size_t)j*32 + b)*96 + cp], accL[cp][b]);
      }
      __syncthreads();
      if (tid == 0) cohs4(&gflag[j*32], (u32)(t+1));
    }
  } else {
    // ---- attn+GRU WG, batch b ----
    const int b = wg - 16;
    u32 wa[64];
    {
      const u32* wp = (const u32*)(Wa + (size_t)(tid&127)*512 + (tid>>7)*128);
#pragma unroll
      for (int i=0;i<64;++i) wa[i] = wp[i];
    }
    u32 ue[16];
    {
      int s = tid & 127, aq = tid >> 7;
      const u32* up = (const u32*)(Uenc + ((size_t)(s*32 + b))*128 + aq*32);
#pragma unroll
      for (int i=0;i<16;++i) ue[i] = up[i];
    }
    if (tid < 128) vL[tid] = Va[tid];
    for (int i = tid; i < 1536; i += 512) brA[i] = brd[i];
    hs[tid] = h0[(size_t)tid*32 + b];
    const short* eb = encx + (size_t)b*1536*128;
    __syncthreads();

    for (int t=0; t<128; ++t){
      // wh = h @ Wa^T (k split 4-way)  [h local in LDS]
      {
        int a = tid & 127, kq2 = tid >> 7;
        float p = 0.f;
        const float* hp2 = &hs[kq2*128];
#pragma unroll 8
        for (int i=0;i<64;++i){
          u32 w2 = wa[i];
          float2 h2 = *(const float2*)(hp2 + 2*i);
          p += bf2f((short)(w2 & 0xffff))*h2.x + bf2f((short)(w2 >> 16))*h2.y;
        }
        whp[a*5 + kq2] = p;
      }
      __syncthreads();
      if (tid < 128) whv[tid] = whp[tid*5]+whp[tid*5+1]+whp[tid*5+2]+whp[tid*5+3];
      __syncthreads();
      // score_s = sum_a tanh(wh_a + Uenc) * v_a (a split 4-way)
      {
        int s = tid & 127, aq = tid >> 7;
        float p = 0.f;
#pragma unroll 4
        for (int i=0;i<16;++i){
          u32 u2 = ue[i];
          int a0 = aq*32 + 2*i;
          p += tanh_fast(whv[a0]   + bf2f((short)(u2 & 0xffff))) * vL[a0];
          p += tanh_fast(whv[a0+1] + bf2f((short)(u2 >> 16)))    * vL[a0+1];
        }
        scp[s*5 + aq] = p;
      }
      __syncthreads();
      if (tid < 128) sc[tid] = scp[tid*5]+scp[tid*5+1]+scp[tid*5+2]+scp[tid*5+3];
      __syncthreads();
      float ev = 0.f;
      if (tid < 128){
        float v = sc[tid], mx = v;
#pragma unroll
        for (int d2=32; d2; d2>>=1) mx = fmaxf(mx, __shfl_xor(mx, d2));
        if ((tid & 63) == 0) red[tid>>6] = mx;
      }
      __syncthreads();
      if (tid < 128){
        float mx = fmaxf(red[0], red[1]);
        ev = __expf(sc[tid] - mx);
        float sm = ev;
#pragma unroll
        for (int d2=32; d2; d2>>=1) sm += __shfl_xor(sm, d2);
        if ((tid & 63) == 0) red[2 + (tid>>6)] = sm;
      }
      __syncthreads();
      if (tid < 128) aL[tid] = ev / (red[2] + red[3]);
      __syncthreads();
      // gxctx: 3 cols/thread from L2-resident ENCX slice
      {
        int col = tid*3;
        float a0=0.f, a1=0.f, a2=0.f;
        const short* e0 = eb + (size_t)col*128;
#pragma unroll
        for (int sb=0; sb<16; ++sb){
          f32x4 av0 = *(const f32x4*)&aL[sb*8];
          f32x4 av1 = *(const f32x4*)&aL[sb*8+4];
          bf16x8 ev0 = *(const bf16x8*)(e0 + sb*8);
          bf16x8 ev1 = *(const bf16x8*)(e0 + 128 + sb*8);
          bf16x8 ev2 = *(const bf16x8*)(e0 + 256 + sb*8);
#pragma unroll
          for (int i=0;i<4;++i){
            a0 += bf2f(ev0[i])*av0[i]; a1 += bf2f(ev1[i])*av0[i]; a2 += bf2f(ev2[i])*av0[i];
            a0 += bf2f(ev0[4+i])*av1[i]; a1 += bf2f(ev1[4+i])*av1[i]; a2 += bf2f(ev2[4+i])*av1[i];
          }
        }
        gxc[col] = a0; gxc[col+1] = a1; gxc[col+2] = a2;
      }
      __syncthreads();
      // prefetch gx (independent of GH), then wait for GH_t
      const short* gx = gxeR + ((size_t)t*32 + b)*1536;
      float gx0 = bf2f(gx[tid])        + gxc[tid];
      float gx1 = bf2f(gx[512 + tid])  + gxc[512 + tid];
      float gx2 = bf2f(gx[1024 + tid]) + gxc[1024 + tid];
      if (tid < 16) pollslot(&gflag[tid*32], (u32)(t+1));
      __syncthreads();
      // read GH slice + pointwise
      {
        size_t gb = ((size_t)(tid>>5)*32 + b)*96 + (tid & 31);
        float gh0 = cohlf(&GH[gb]);
        float gh1 = cohlf(&GH[gb + 32]);
        float gh2 = cohlf(&GH[gb + 64]);
        float z = sig_p(gx0 + gh0 + brA[tid]);
        float r = sig_p(gx1 + gh1 + brA[512 + tid]);
        float hcand = tanhf(gx2 + r*(gh2 + brA[1024 + tid]));
        float hp = hs[tid];
        float hn = z*hp + (1.f-z)*hcand;
        hs[tid] = hn;
        hb[tid] = f2bf(hn);
        decRow[((size_t)t*32 + b)*512 + tid] = f2bf(hn);
      }
      __syncthreads();
      if (tid < 256){
        u32 pv = ((u32)(unsigned short)hb[2*tid+1]<<16) | (u32)(unsigned short)hb[2*tid];
        cohs4(&hrowB[((size_t)((t+1)&1)*32 + b)*256 + tid], pv);
      }
      __syncthreads();
      if (tid == 0) cohs4(&hflag[b*32], (u32)(t+1));
    }
  }
}

// ---------------- softmax finish ----------------
__global__ void scale_rows(float* __restrict__ out, const float* __restrict__ psum,
                           int ncols, int w){
  int r = blockIdx.x;
  __shared__ float ssum[256];
  float s = 0.f;
  for (int i = threadIdx.x; i < w; i += 256) s += psum[(size_t)r*w + i];
  ssum[threadIdx.x] = s; __syncthreads();
  for (int d = 128; d; d >>= 1){
    if (threadIdx.x < d) ssum[threadIdx.x] += ssum[threadIdx.x + d];
    __syncthreads();
  }
  float v = 1.f/ssum[0];
  float* p = out + (size_t)r*ncols;
  for (int i = threadIdx.x; i < ncols; i += 256) p[i] *= v;
}

// ---------------- host ----------------
extern "C" void kernel_launch(void* const* d_in, const int* in_sizes, int n_in,
                              void* d_out, int out_size, void* d_ws, size_t ws_size,
                              hipStream_t stream)
{
  const int*   tokens=(const int*)  d_in[0];
  const float* emb  =(const float*)d_in[1];
  const float* Wx_f =(const float*)d_in[2];
  const float* Wh_f =(const float*)d_in[3];
  const float* bi_f =(const float*)d_in[4];
  const float* br_f =(const float*)d_in[5];
  const float* Wx_b =(const float*)d_in[6];
  const float* Wh_b =(const float*)d_in[7];
  const float* bi_b =(const float*)d_in[8];
  const float* br_b =(const float*)d_in[9];
  const float* W_a  =(const float*)d_in[10];
  const float* U_a  =(const float*)d_in[11];
  const float* V_a  =(const float*)d_in[12];
  const float* Wx_d =(const float*)d_in[13];
  const float* Wh_d =(const float*)d_in[14];
  const float* bi_d =(const float*)d_in[15];
  const float* br_d =(const float*)d_in[16];
  const float* Wo   =(const float*)d_in[17];
  const float* bo   =(const float*)d_in[18];

  const int NV = 32001, NVP = 32128, NCB = 251;

  char* base = (char*)d_ws; size_t off = 0;
  auto alloc = [&](size_t bytes)->char*{
    off = (off + 255) & ~(size_t)255;
    char* p = base + off; off += bytes; return p;
  };
  u32*   flags  = (u32*)  alloc(16384);  // enc [0..1023], hflag [1024..2047], gflag [2048..2559]
  short* X      = (short*)alloc((size_t)4096*256*2);
  short* WxfT   = (short*)alloc((size_t)1536*256*2);
  short* WxbT   = (short*)alloc((size_t)1536*256*2);
  short* WhfT   = (short*)alloc((size_t)1536*512*2);
  short* WhbT   = (short*)alloc((size_t)1536*512*2);
  short* WhdT   = (short*)alloc((size_t)1536*512*2);
  short* WxeT   = (short*)alloc((size_t)1536*1024*2);
  short* WxcT   = (short*)alloc((size_t)1536*1024*2);
  short* WoT    = (short*)alloc((size_t)NVP*512*2);
  short* UaB    = (short*)alloc((size_t)128*1024*2);
  short* WaB    = (short*)alloc((size_t)128*512*2);
  short* gxfT   = (short*)alloc((size_t)128*1536*32*2);
  short* gxbT   = (short*)alloc((size_t)128*1536*32*2);
  short* encT   = (short*)alloc((size_t)128*1024*32*2);
  short* encRow = (short*)alloc((size_t)4096*1024*2);
  short* Uenc   = (short*)alloc((size_t)4096*128*2);
  short* gxeR   = (short*)alloc((size_t)4096*1536*2);    // [(t*32+b)][1536]
  short* encxT1 = (short*)alloc((size_t)128*1536*32*2);  // [s][1536][32]
  short* encx   = (short*)alloc((size_t)32*1536*128*2);  // [b][1536][128]
  short* decRow = (short*)alloc((size_t)4096*512*2);
  float* hT_e   = (float*)alloc((size_t)2*2*512*32*4);
  u32*   hrowB_e= (u32*)  alloc((size_t)2*2*32*256*4);
  u32*   hrowB_d= (u32*)  alloc((size_t)2*32*256*4);
  float* GH     = (float*)alloc((size_t)16*32*96*4);
  float* psum   = (float*)alloc((size_t)4096*2*NCB*4);

  hipMemsetAsync(flags, 0, 16384, stream);
  hipMemsetAsync(hT_e, 0, (size_t)2*2*512*32*4, stream);
  hipMemsetAsync(hrowB_e, 0, (size_t)2*2*32*256*4, stream);

  // weight conversions (all BT = [N][K] bf16)
  tconv<<<dim3(1536/32,256/32),dim3(32,8),0,stream>>>(Wx_f, WxfT, 256, 1536, 1536);
  tconv<<<dim3(1536/32,256/32),dim3(32,8),0,stream>>>(Wx_b, WxbT, 256, 1536, 1536);
  tconv<<<dim3(1536/32,512/32),dim3(32,8),0,stream>>>(Wh_f, WhfT, 512, 1536, 1536);
  tconv<<<dim3(1536/32,512/32),dim3(32,8),0,stream>>>(Wh_b, WhbT, 512, 1536, 1536);
  tconv<<<dim3(1536/32,512/32),dim3(32,8),0,stream>>>(Wh_d, WhdT, 512, 1536, 1536);
  tconv<<<dim3(1536/32,1024/32),dim3(32,8),0,stream>>>(Wx_d,                    WxeT, 1024, 1536, 1536);
  tconv<<<dim3(1536/32,1024/32),dim3(32,8),0,stream>>>(Wx_d+(size_t)1024*1536,  WxcT, 1024, 1536, 1536);
  tconv<<<dim3(NVP/32,512/32),dim3(32,8),0,stream>>>(Wo, WoT, 512, NV, NVP);
  cvt1d<<<(128*512+255)/256,256,0,stream>>>(W_a, WaB, 128*512);
  cvt1d<<<(128*1024+255)/256,256,0,stream>>>(U_a, UaB, 128*1024);

  embed_k<<<4096,256,0,stream>>>(tokens, emb, X);

  gemm_k<1><<<dim3(12,32),256,0,stream>>>(X, WxfT, bi_f, gxfT, nullptr, 1536, 256, 1536);
  gemm_k<1><<<dim3(12,32),256,0,stream>>>(X, WxbT, bi_b, gxbT, nullptr, 1536, 256, 1536);

  enc_scan<<<32,512,0,stream>>>(gxfT, gxbT, WhfT, WhbT, br_f, br_b,
                                hT_e, hrowB_e, encT, flags);

  btrans<<<dim3(1024/32,128),dim3(32,8),0,stream>>>(encT, encRow, 1024);

  gemm_k<3><<<dim3(1,32),256,0,stream>>>(encRow, UaB, nullptr, Uenc, nullptr, 128, 1024, 128);
  gemm_k<3><<<dim3(12,32),256,0,stream>>>(encRow, WxeT, bi_d, gxeR, nullptr, 1536, 1024, 1536);
  gemm_k<1><<<dim3(12,32),256,0,stream>>>(encRow, WxcT, nullptr, encxT1, nullptr, 1536, 1024, 1536);
  etrans<<<1536,256,0,stream>>>(encxT1, encx);

  // decoder h0 = backward final h (dir=1, buf0)
  dec_init<<<32,256,0,stream>>>(hT_e + 32768, hrowB_d);

  dec_scan<<<48,512,0,stream>>>(gxeR, encx, WhdT, br_d, WaB, Uenc, V_a,
                                hT_e + 32768, hrowB_d, GH, decRow,
                                &flags[1024], &flags[2048]);

  gemm_k<2><<<dim3(NCB,32),256,0,stream>>>(decRow, WoT, bo, d_out, psum, NV, 512, NV);

  scale_rows<<<4096,256,0,stream>>>((float*)d_out, psum, NV, 2*NCB);
}